// Round 9
// baseline (1197.951 us; speedup 1.0000x reference)
//
#include <hip/hip_runtime.h>
#include <hip/hip_bf16.h>

#define T_TOK 4096
#define H_DIM 4096
#define I_DIM 2048
#define N_EXP 8
#define TOPK  2
#define NPAIR (T_TOK*TOPK)          // 8192
#define BM    128                   // fallback gemm2 M-tile
#define BK    32
#define MAXT  (NPAIR/BM + N_EXP)    // 72
#define BM1   256
#define BN1   128
#define MAXT1 (NPAIR/BM1 + N_EXP)   // 40

// ---- tiled-workspace offsets (bytes) ----
#define HT_OFF   ((size_t)1 << 20)
#define W0_OFF   ((size_t)45 << 20)                 // Wot (gemm2 weights)
#define W1_OFF   (W0_OFF + 134217728ull)
#define AT_OFF   (W1_OFF + 134217728ull)
#define NEED_NEW (AT_OFF + 83886080ull)             // ~381 MB (unchanged, proven)

typedef __attribute__((ext_vector_type(8))) short  bf16x8;
typedef __attribute__((ext_vector_type(4))) float  f32x4v;

__device__ __forceinline__ short f2bf(float f) {
    __hip_bfloat16 h = __float2bfloat16(f);
    return __builtin_bit_cast(short, h);
}

__device__ __forceinline__ bf16x8 pack8(f32x4v a, f32x4v b) {
    bf16x8 r;
    r[0]=f2bf(a[0]); r[1]=f2bf(a[1]); r[2]=f2bf(a[2]); r[3]=f2bf(a[3]);
    r[4]=f2bf(b[0]); r[5]=f2bf(b[1]); r[6]=f2bf(b[2]); r[7]=f2bf(b[3]);
    return r;
}

__device__ __forceinline__ void load_lds16(const short* g, short* l) {
    __builtin_amdgcn_global_load_lds(
        (const __attribute__((address_space(1))) void*)g,
        (__attribute__((address_space(3))) void*)l, 16, 0, 0);
}

// ---------------- fp32 -> bf16 plain (fallback X path) ----------------
__global__ void cvt_kernel(const float* __restrict__ X, short* __restrict__ Xbf) {
    const size_t i = ((size_t)blockIdx.x * 256 + threadIdx.x) * 8;
    f32x4v a = *(const f32x4v*)(X + i);
    f32x4v b = *(const f32x4v*)(X + i + 4);
    *(bf16x8*)(Xbf + i) = pack8(a, b);
}

// ---------------- routing ----------------
__global__ void route_kernel(const int* __restrict__ ids, const float* __restrict__ wts,
                             int* __restrict__ pair_token, float* __restrict__ pair_w,
                             int* __restrict__ tile_expert, int* __restrict__ tile_row0,
                             int* __restrict__ tile_rows,
                             int* __restrict__ t1_expert, int* __restrict__ t1_row0,
                             int* __restrict__ t1_rows)
{
    __shared__ int scn[256][N_EXP];
    const int tid = threadIdx.x;
    const int PPT = NPAIR / 256;
    const int base = tid * PPT;

    int c[N_EXP], orig[N_EXP];
    #pragma unroll
    for (int e = 0; e < N_EXP; ++e) c[e] = 0;
    for (int p = 0; p < PPT; ++p) c[ids[base + p]]++;
    #pragma unroll
    for (int e = 0; e < N_EXP; ++e) { orig[e] = c[e]; scn[tid][e] = c[e]; }
    __syncthreads();

    for (int off = 1; off < 256; off <<= 1) {
        int add[N_EXP];
        #pragma unroll
        for (int e = 0; e < N_EXP; ++e) add[e] = (tid >= off) ? scn[tid - off][e] : 0;
        __syncthreads();
        #pragma unroll
        for (int e = 0; e < N_EXP; ++e) { c[e] += add[e]; scn[tid][e] = c[e]; }
        __syncthreads();
    }

    int segs[N_EXP + 1];
    {
        int run = 0;
        #pragma unroll
        for (int e = 0; e < N_EXP; ++e) { segs[e] = run; run += scn[255][e]; }
        segs[N_EXP] = run;
    }
    int pos[N_EXP];
    #pragma unroll
    for (int e = 0; e < N_EXP; ++e) pos[e] = segs[e] + c[e] - orig[e];

    for (int p = 0; p < PPT; ++p) {
        int pp = base + p;
        int e = ids[pp];
        int q = pos[e]++;
        pair_token[q] = pp / TOPK;
        pair_w[q]     = wts[pp];
    }

    if (tid == 0) {
        int t = 0;
        for (int e = 0; e < N_EXP; ++e) {
            int s = segs[e], en = segs[e + 1];
            for (int r = s; r < en; r += BM) {
                tile_expert[t] = e; tile_row0[t] = r; tile_rows[t] = min(BM, en - r); ++t;
            }
        }
        for (; t < MAXT; ++t) { tile_expert[t] = 0; tile_row0[t] = 0; tile_rows[t] = 0; }

        t = 0;
        for (int e = 0; e < N_EXP; ++e) {
            int s = segs[e], en = segs[e + 1];
            for (int r = s; r < en; r += BM1) {
                t1_expert[t] = e; t1_row0[t] = r; t1_rows[t] = min(BM1, en - r); ++t;
            }
        }
        for (; t < MAXT1; ++t) { t1_expert[t] = 0; t1_row0[t] = 0; t1_rows[t] = 0; }
    }
}

// ================= coalesced LDS-transpose preps (aprep + woprep only) =================
#define PRP 132

// Wo (E,H,I) fp32 -> Wot [e][hb][kt 64][q 4][r 256][x 8]
__global__ __launch_bounds__(256) void woprep_kernel(const float* __restrict__ W, short* __restrict__ Wt) {
    const int bid = blockIdx.x;          // 8 * 16 * 2 * 16 = 4096
    const int e   = bid >> 9;
    const int hb  = (bid >> 5) & 15;
    const int rh  = (bid >> 4) & 1;
    const int ktg = bid & 15;
    __shared__ short lds[128][PRP];
    const int tid = threadIdx.x;
    const float* src0 = W + ((size_t)(e * 4096 + hb * 256 + rh * 128)) * 2048 + ktg * 128;
    #pragma unroll
    for (int it = 0; it < 8; ++it) {
        int r  = it * 16 + (tid >> 4);
        int hc = (tid & 15) * 8;
        const float* s = src0 + (size_t)r * 2048 + hc;
        f32x4v a = *(const f32x4v*)s;
        f32x4v b = *(const f32x4v*)(s + 4);
        *(bf16x8*)&lds[r][hc] = pack8(a, b);
    }
    __syncthreads();
    short* dst = Wt + (((size_t)(e * 16 + hb) * 64 + ktg * 4) * 8192) + rh * 1024;
    #pragma unroll
    for (int it = 0; it < 8; ++it) {
        int off = it * 2048 + tid * 8;
        int ktl = off >> 12;
        int q   = (off >> 10) & 3;
        int rl  = (off >> 3) & 127;
        bf16x8 v = *(const bf16x8*)&lds[rl][ktl * 32 + q * 8];
        *(bf16x8*)(dst + (size_t)ktl * 8192 + q * 2048 + rl * 8) = v;
    }
}

// X gather -> At [tile][kt 128][q 4][r 256][x 8]
__global__ __launch_bounds__(256) void aprep_kernel(const float* __restrict__ X,
                             const int* __restrict__ pair_token,
                             const int* __restrict__ t1_row0, const int* __restrict__ t1_rows,
                             short* __restrict__ At) {
    const int bid  = blockIdx.x;         // 40 * 2 * 32 = 2560
    const int tile = bid >> 6;
    const int rh   = (bid >> 5) & 1;
    const int ktg  = bid & 31;
    const int rows = t1_rows[tile];
    if (rows == 0) return;
    const int row0 = t1_row0[tile];
    __shared__ short lds[128][PRP];
    const int tid = threadIdx.x;
    #pragma unroll
    for (int it = 0; it < 8; ++it) {
        int r  = it * 16 + (tid >> 4);
        int hc = (tid & 15) * 8;
        int tok = pair_token[row0 + min(rh * 128 + r, rows - 1)];
        const float* s = X + (size_t)tok * 4096 + ktg * 128 + hc;
        f32x4v a = *(const f32x4v*)s;
        f32x4v b = *(const f32x4v*)(s + 4);
        *(bf16x8*)&lds[r][hc] = pack8(a, b);
    }
    __syncthreads();
    short* dst = At + (((size_t)tile * 128 + ktg * 4) * 8192) + rh * 1024;
    #pragma unroll
    for (int it = 0; it < 8; ++it) {
        int off = it * 2048 + tid * 8;
        int ktl = off >> 12;
        int q   = (off >> 10) & 3;
        int rl  = (off >> 3) & 127;
        bf16x8 v = *(const bf16x8*)&lds[rl][ktl * 32 + q * 8];
        *(bf16x8*)(dst + (size_t)ktl * 8192 + q * 2048 + rl * 8) = v;
    }
}

// ================= GEMM1: 4-phase fine interleave, A gload_lds ring, B fp32 reg-staged =================
// LDS stage (16B slots): A [0..1023]=q*256+r ; B0 [1024..1535]=q*128+(r^(q<<2)) ; B1 [1536..2047]

__global__ __launch_bounds__(512, 2) void gemm1b_kernel(
    const short* __restrict__ At,       // [40][128][4][256][8] bf16 tiled
    const float* __restrict__ Wi0,      // [E][I][H] fp32
    const float* __restrict__ Wi1,
    const float* __restrict__ pair_w,
    const int* __restrict__ t1_expert, const int* __restrict__ t1_row0,
    const int* __restrict__ t1_rows,
    short* __restrict__ Ht)             // [40][64][4][256][8]
{
    const int b    = blockIdx.x;
    const int xcd  = b & 7;
    const int i    = b >> 3;
    const int tile  = xcd * 5 + (i >> 4);
    const int n0idx = i & 15;
    const int rows = t1_rows[tile];
    if (rows == 0) return;
    const int e    = t1_expert[tile];
    const int row0 = t1_row0[tile];
    const int n0   = n0idx * BN1;

    __shared__ short stg[4][16384];      // 128 KB, 4-image ring
    __shared__ float sPw[BM1];

    const int tid  = threadIdx.x;
    const int lane = tid & 63;
    const int w    = tid >> 6;
    const int wof  = w * 512;

    if (tid < BM1) sPw[tid] = (tid < rows) ? pair_w[row0 + tid] : 0.f;
    __syncthreads();

    const short* aT = At + (size_t)tile * 1048576 + (size_t)tid * 8;

    // B fp32 direct: thread -> row tid>>2 (0..127), col-chunk (tid&3)*8
    const int brow = tid >> 2;
    const int bq   = tid & 3;
    const float* b0p = Wi0 + ((size_t)e * I_DIM + n0 + brow) * H_DIM + bq * 8;
    const float* b1p = Wi1 + ((size_t)e * I_DIM + n0 + brow) * H_DIM + bq * 8;
    const int browz  = brow ^ (bq << 2);               // write-conflict swizzle (4-way -> 2-way)
    const int slotB0 = (1024 + bq * 128 + browz) * 8;
    const int slotB1 = (1536 + bq * 128 + browz) * 8;

    const int wr = w >> 1, wc = w & 1;
    const int frow = lane & 15, fsel = lane >> 4;
    const int rBz  = ((wc * 64 + frow) ^ (fsel << 2)); // read-side matching swizzle base (nf added below)

    f32x4v accg[4][4], accu[4][4];
    #pragma unroll
    for (int mf = 0; mf < 4; ++mf)
        #pragma unroll
        for (int nf = 0; nf < 4; ++nf) { accg[mf][nf] = (f32x4v)0.f; accu[mf][nf] = (f32x4v)0.f; }

    f32x4v rb0a, rb0b, rb1a, rb1b;

#define STAGEA0(s, kt) load_lds16(aT + (size_t)(kt) * 8192,        &stg[s][0] + wof)
#define STAGEA1(s, kt) load_lds16(aT + (size_t)(kt) * 8192 + 4096, &stg[s][0] + wof + 4096)

#define LOADB(kt) do { \
        const float* p0_ = b0p + (size_t)(kt) * 32; \
        const float* p1_ = b1p + (size_t)(kt) * 32; \
        rb0a = *(const f32x4v*)p0_; rb0b = *(const f32x4v*)(p0_ + 4); \
        rb1a = *(const f32x4v*)p1_; rb1b = *(const f32x4v*)(p1_ + 4); \
    } while (0)

#define WRITEB(s) do { \
        short* st_ = &stg[s][0]; \
        *(bf16x8*)(st_ + slotB0) = pack8(rb0a, rb0b); \
        *(bf16x8*)(st_ + slotB1) = pack8(rb1a, rb1b); \
    } while (0)

    // prologue: A(0..2) in flight, B(0) loaded+written
    STAGEA0(0, 0); STAGEA1(0, 0);
    STAGEA0(1, 1); STAGEA1(1, 1);
    STAGEA0(2, 2); STAGEA1(2, 2);
    LOADB(0);
    asm volatile("s_waitcnt vmcnt(0)" ::: "memory");
    WRITEB(0);
    asm volatile("s_waitcnt lgkmcnt(0)" ::: "memory");
    __builtin_amdgcn_s_barrier();
    __builtin_amdgcn_sched_barrier(0);

    const int KT = H_DIM / 32;   // 128
    for (int kt = 0; kt < KT; ++kt) {
        const short* st = &stg[kt & 3][0];
        bf16x8 af[4], b0f[4], b1f[4];

        // ---- phase 0: af[0..1] + b0f reads; issue LOADB(kt+1); 8 gate MFMA ----
        if (kt + 1 < KT) LOADB(kt + 1);
        #pragma unroll
        for (int mf = 0; mf < 2; ++mf)
            af[mf] = *(const bf16x8*)(st + (fsel * 256 + wr * 64 + mf * 16 + frow) * 8);
        #pragma unroll
        for (int nf = 0; nf < 4; ++nf)
            b0f[nf] = *(const bf16x8*)(st + (1024 + fsel * 128 + (rBz ^ (nf * 16))) * 8);
        __builtin_amdgcn_s_barrier();
        asm volatile("s_waitcnt lgkmcnt(0)" ::: "memory");
        __builtin_amdgcn_sched_barrier(0);
        __builtin_amdgcn_s_setprio(1);
        #pragma unroll
        for (int nf = 0; nf < 4; ++nf)
            #pragma unroll
            for (int mf = 0; mf < 2; ++mf)
                accg[mf][nf] = __builtin_amdgcn_mfma_f32_16x16x32_bf16(af[mf], b0f[nf], accg[mf][nf], 0, 0, 0);
        __builtin_amdgcn_s_setprio(0);
        __builtin_amdgcn_sched_barrier(0);
        __builtin_amdgcn_s_barrier();

        // ---- phase 1: b1f reads; issue A-gload#0(kt+3); 8 up MFMA ----
        if (kt + 3 < KT) STAGEA0((kt + 3) & 3, kt + 3);
        #pragma unroll
        for (int nf = 0; nf < 4; ++nf)
            b1f[nf] = *(const bf16x8*)(st + (1536 + fsel * 128 + (rBz ^ (nf * 16))) * 8);
        __builtin_amdgcn_s_barrier();
        asm volatile("s_waitcnt lgkmcnt(0)" ::: "memory");
        __builtin_amdgcn_sched_barrier(0);
        __builtin_amdgcn_s_setprio(1);
        #pragma unroll
        for (int nf = 0; nf < 4; ++nf)
            #pragma unroll
            for (int mf = 0; mf < 2; ++mf)
                accu[mf][nf] = __builtin_amdgcn_mfma_f32_16x16x32_bf16(af[mf], b1f[nf], accu[mf][nf], 0, 0, 0);
        __builtin_amdgcn_s_setprio(0);
        __builtin_amdgcn_sched_barrier(0);
        __builtin_amdgcn_s_barrier();

        // ---- phase 2: af[2..3] reads; issue A-gload#1(kt+3); 8 gate MFMA ----
        if (kt + 3 < KT) STAGEA1((kt + 3) & 3, kt + 3);
        #pragma unroll
        for (int mf = 2; mf < 4; ++mf)
            af[mf] = *(const bf16x8*)(st + (fsel * 256 + wr * 64 + mf * 16 + frow) * 8);
        __builtin_amdgcn_s_barrier();
        asm volatile("s_waitcnt lgkmcnt(0)" ::: "memory");
        __builtin_amdgcn_sched_barrier(0);
        __builtin_amdgcn_s_setprio(1);
        #pragma unroll
        for (int nf = 0; nf < 4; ++nf)
            #pragma unroll
            for (int mf = 2; mf < 4; ++mf)
                accg[mf][nf] = __builtin_amdgcn_mfma_f32_16x16x32_bf16(af[mf], b0f[nf], accg[mf][nf], 0, 0, 0);
        __builtin_amdgcn_s_setprio(0);
        __builtin_amdgcn_sched_barrier(0);
        __builtin_amdgcn_s_barrier();

        // ---- phase 3: 8 up MFMA ----
        __builtin_amdgcn_s_setprio(1);
        #pragma unroll
        for (int nf = 0; nf < 4; ++nf)
            #pragma unroll
            for (int mf = 2; mf < 4; ++mf)
                accu[mf][nf] = __builtin_amdgcn_mfma_f32_16x16x32_bf16(af[mf], b1f[nf], accu[mf][nf], 0, 0, 0);
        __builtin_amdgcn_s_setprio(0);
        __builtin_amdgcn_sched_barrier(0);

        // ---- commit: counted vmcnt; write B(kt+1); publish image kt+1 ----
        if (kt + 1 < KT) {
            if (kt + 3 < KT) asm volatile("s_waitcnt vmcnt(2)" ::: "memory");
            else             asm volatile("s_waitcnt vmcnt(0)" ::: "memory");
            WRITEB((kt + 1) & 3);
            asm volatile("s_waitcnt lgkmcnt(0)" ::: "memory");
            __builtin_amdgcn_s_barrier();
            __builtin_amdgcn_sched_barrier(0);
        }
    }
#undef STAGEA0
#undef STAGEA1
#undef LOADB
#undef WRITEB

    // epilogue: silu(g)*u*pw -> Ht (tiled layout)
    const int r4 = fsel * 4;
    #pragma unroll
    for (int mf = 0; mf < 4; ++mf)
        #pragma unroll
        for (int nf = 0; nf < 4; ++nf) {
            const int col = n0 + wc * 64 + nf * 16 + frow;
            const size_t cbase = (((size_t)tile * 64 + (col >> 5)) * 8192)
                               + (size_t)((col >> 3) & 3) * 2048 + (col & 7);
            #pragma unroll
            for (int j = 0; j < 4; ++j) {
                int rr = wr * 64 + mf * 16 + r4 + j;
                if (rr < rows) {
                    float g = accg[mf][nf][j];
                    float u = accu[mf][nf][j];
                    float sig = 1.f / (1.f + __expf(-g));
                    Ht[cbase + (size_t)rr * 8] = f2bf(g * sig * u * sPw[rr]);
                }
            }
        }
}

// ================= GEMM2 (UNCHANGED — control) =================
__global__ __launch_bounds__(512, 2) void gemm2b_kernel(
    const short* __restrict__ Ht,       // [40][64][4][256][8]
    const short* __restrict__ Wot,      // [E][16][64][4][256][8]
    const int* __restrict__ pair_token,
    const int* __restrict__ t1_expert, const int* __restrict__ t1_row0,
    const int* __restrict__ t1_rows,
    float* __restrict__ out)            // [T][H]
{
    const int b    = blockIdx.x;
    const int xcd  = b & 7;
    const int i    = b >> 3;
    const int tile  = xcd * 5 + (i >> 4);
    const int n0idx = i & 15;            // over H/256
    const int rows = t1_rows[tile];
    if (rows == 0) return;
    const int e    = t1_expert[tile];
    const int row0 = t1_row0[tile];
    const int n0   = n0idx * 256;

    __shared__ short stg[4][16384];      // 128 KB
    __shared__ int   sTok[BM1];

    const int tid  = threadIdx.x;
    const int lane = tid & 63;
    const int w    = tid >> 6;
    const int wof  = w * 512;

    if (tid < BM1) sTok[tid] = pair_token[row0 + min(tid, rows - 1)];
    __syncthreads();

    const short* aT = Ht  + (size_t)tile * 524288 + (size_t)tid * 8;
    const short* bT = Wot + ((size_t)e * 16 + n0idx) * 524288 + (size_t)tid * 8;

    const int wr = w >> 1, wc = w & 1;
    const int frow = lane & 15, fsel = lane >> 4;

    f32x4v acc[4][8];
    #pragma unroll
    for (int mf = 0; mf < 4; ++mf)
        #pragma unroll
        for (int nf = 0; nf < 8; ++nf) acc[mf][nf] = (f32x4v)0.f;

#define STAGE2(s, kt) do { \
        short* st_ = &stg[s][0] + wof; \
        const size_t ko_ = (size_t)(kt); \
        load_lds16(aT + ko_ * 8192,        st_); \
        load_lds16(aT + ko_ * 8192 + 4096, st_ + 4096); \
        load_lds16(bT + ko_ * 8192,        st_ + 8192); \
        load_lds16(bT + ko_ * 8192 + 4096, st_ + 12288); \
    } while (0)

#define COMPUTE2(s) do { \
        const short* st_ = &stg[s][0]; \
        bf16x8 af[4], bf_[8]; \
        _Pragma("unroll") \
        for (int mf = 0; mf < 4; ++mf) \
            af[mf] = *(const bf16x8*)(st_ + (fsel * 256 + wr * 64 + mf * 16 + frow) * 8); \
        _Pragma("unroll") \
        for (int nf = 0; nf < 8; ++nf) \
            bf_[nf] = *(const bf16x8*)(st_ + (1024 + fsel * 256 + wc * 128 + nf * 16 + frow) * 8); \
        __builtin_amdgcn_s_setprio(1); \
        _Pragma("unroll") \
        for (int nf = 0; nf < 8; ++nf) \
            _Pragma("unroll") \
            for (int mf = 0; mf < 4; ++mf) \
                acc[mf][nf] = __builtin_amdgcn_mfma_f32_16x16x32_bf16(af[mf], bf_[nf], acc[mf][nf], 0, 0, 0); \
        __builtin_amdgcn_s_setprio(0); \
    } while (0)

    STAGE2(0, 0); STAGE2(1, 1); STAGE2(2, 2);
    asm volatile("s_waitcnt vmcnt(8)" ::: "memory");
    __builtin_amdgcn_s_barrier();
    __builtin_amdgcn_sched_barrier(0);

    const int KT = I_DIM / 32;   // 64
    for (int kt = 0; kt < KT; ++kt) {
        const int cur = kt & 3;
        if (kt + 3 < KT) STAGE2((kt + 3) & 3, kt + 3);
        COMPUTE2(cur);
        if (kt + 1 < KT) {
            __builtin_amdgcn_sched_barrier(0);
            if (kt + 3 < KT)      asm volatile("s_waitcnt vmcnt(8)" ::: "memory");
            else if (kt + 2 < KT) asm volatile("s_waitcnt vmcnt(4)" ::: "memory");
            else                  asm volatile("s_waitcnt vmcnt(0)" ::: "memory");
            __builtin_amdgcn_s_barrier();
            __builtin_amdgcn_sched_barrier(0);
        }
    }
#undef STAGE2
#undef COMPUTE2

    const int r4 = fsel * 4;
    #pragma unroll
    for (int mf = 0; mf < 4; ++mf)
        #pragma unroll
        for (int nf = 0; nf < 8; ++nf)
            #pragma unroll
            for (int j = 0; j < 4; ++j) {
                int rr = wr * 64 + mf * 16 + r4 + j;
                if (rr < rows) {
                    int col = n0 + wc * 128 + nf * 16 + frow;
                    atomicAdd(out + (size_t)sTok[rr] * H_DIM + col, acc[mf][nf][j]);
                }
            }
}

// ================= FALLBACK PATH (R3) =================
__global__ __launch_bounds__(512, 2) void gemm1_kernel(
    const short* __restrict__ Xbf, const float* __restrict__ Wi0, const float* __restrict__ Wi1,
    const int* __restrict__ pair_token, const float* __restrict__ pair_w,
    const int* __restrict__ t1_expert, const int* __restrict__ t1_row0, const int* __restrict__ t1_rows,
    short* __restrict__ Hbuf)
{
    const int tile = blockIdx.x;
    const int rows = t1_rows[tile];
    if (rows == 0) return;
    const int e    = t1_expert[tile];
    const int row0 = t1_row0[tile];
    const int n0   = blockIdx.y * BN1;

    __shared__ short sA [2][BM1][64];
    __shared__ short sB0[2][BN1][64 + 8];
    __shared__ short sB1[2][BN1][64 + 8];
    __shared__ int   sTok[BM1];
    __shared__ float sPw [BM1];

    const int tid  = threadIdx.x;
    const int lane = tid & 63;
    const int w    = tid >> 6;

    if (tid < BM1) {
        int tr = min(tid, rows - 1);
        sTok[tid] = pair_token[row0 + tr];
        sPw[tid]  = (tid < rows) ? pair_w[row0 + tid] : 0.f;
    }
    __syncthreads();

    const short* aSrc[4];
    #pragma unroll
    for (int i = 0; i < 4; ++i) {
        int r = w * 32 + i * 8 + (lane >> 3);
        int j = lane & 7;
        aSrc[i] = Xbf + (size_t)sTok[r] * H_DIM + ((j ^ (r & 7)) * 8);
    }

    const int brow = tid >> 2;
    const int bq   = tid & 3;
    const size_t wboff = ((size_t)e * I_DIM + (n0 + brow)) * H_DIM + bq * 16;
    const float* b0p = Wi0 + wboff;
    const float* b1p = Wi1 + wboff;

    const int wr   = w >> 1;
    const int wc   = w & 1;
    const int frow = lane & 15;
    const int fsel = lane >> 4;

    f32x4v accg[4][4], accu[4][4];
    #pragma unroll
    for (int mf = 0; mf < 4; ++mf)
        #pragma unroll
        for (int nf = 0; nf < 4; ++nf) { accg[mf][nf] = (f32x4v)0.f; accu[mf][nf] = (f32x4v)0.f; }

    f32x4v rb0[4], rb1[4];

    #pragma unroll
    for (int i = 0; i < 4; ++i)
        load_lds16(aSrc[i], &sA[0][w * 32 + i * 8][0]);
    #pragma unroll
    for (int i = 0; i < 4; ++i) { rb0[i] = *(const f32x4v*)(b0p + i * 4); rb1[i] = *(const f32x4v*)(b1p + i * 4); }
    {
        short* d0 = &sB0[0][brow][bq * 16];
        *(bf16x8*)d0       = pack8(rb0[0], rb0[1]);
        *(bf16x8*)(d0 + 8) = pack8(rb0[2], rb0[3]);
        short* d1 = &sB1[0][brow][bq * 16];
        *(bf16x8*)d1       = pack8(rb1[0], rb1[1]);
        *(bf16x8*)(d1 + 8) = pack8(rb1[2], rb1[3]);
    }
    __syncthreads();

    const int KT = H_DIM / 64;
    for (int kt = 0; kt < KT; ++kt) {
        const int cur = kt & 1, nxt = cur ^ 1;
        if (kt + 1 < KT) {
            #pragma unroll
            for (int i = 0; i < 4; ++i)
                load_lds16(aSrc[i] + (kt + 1) * 64, &sA[nxt][w * 32 + i * 8][0]);
            const float* p0 = b0p + (kt + 1) * 64;
            const float* p1 = b1p + (kt + 1) * 64;
            #pragma unroll
            for (int i = 0; i < 4; ++i) { rb0[i] = *(const f32x4v*)(p0 + i * 4); rb1[i] = *(const f32x4v*)(p1 + i * 4); }
        }
        #pragma unroll
        for (int h = 0; h < 2; ++h) {
            bf16x8 af[4], b0f[4], b1f[4];
            #pragma unroll
            for (int mf = 0; mf < 4; ++mf) {
                int ar = wr * 64 + mf * 16 + frow;
                int c  = (h * 4 + fsel) ^ (ar & 7);
                af[mf] = *(const bf16x8*)((const char*)&sA[cur][0][0] + ar * 128 + c * 16);
            }
            #pragma unroll
            for (int nf = 0; nf < 4; ++nf) {
                int br = wc * 64 + nf * 16 + frow;
                b0f[nf] = *(const bf16x8*)&sB0[cur][br][h * 32 + fsel * 8];
                b1f[nf] = *(const bf16x8*)&sB1[cur][br][h * 32 + fsel * 8];
            }
            #pragma unroll
            for (int nf = 0; nf < 4; ++nf)
                #pragma unroll
                for (int mf = 0; mf < 4; ++mf) {
                    accg[mf][nf] = __builtin_amdgcn_mfma_f32_16x16x32_bf16(af[mf], b0f[nf], accg[mf][nf], 0, 0, 0);
                    accu[mf][nf] = __builtin_amdgcn_mfma_f32_16x16x32_bf16(af[mf], b1f[nf], accu[mf][nf], 0, 0, 0);
                }
        }
        if (kt + 1 < KT) {
            short* d0 = &sB0[nxt][brow][bq * 16];
            *(bf16x8*)d0       = pack8(rb0[0], rb0[1]);
            *(bf16x8*)(d0 + 8) = pack8(rb0[2], rb0[3]);
            short* d1 = &sB1[nxt][brow][bq * 16];
            *(bf16x8*)d1       = pack8(rb1[0], rb1[1]);
            *(bf16x8*)(d1 + 8) = pack8(rb1[2], rb1[3]);
        }
        __syncthreads();
    }

    const int r4 = fsel * 4;
    #pragma unroll
    for (int mf = 0; mf < 4; ++mf)
        #pragma unroll
        for (int nf = 0; nf < 4; ++nf)
            #pragma unroll
            for (int j = 0; j < 4; ++j) {
                int rr = wr * 64 + mf * 16 + r4 + j;
                if (rr < rows) {
                    float g = accg[mf][nf][j];
                    float u = accu[mf][nf][j];
                    float sig = 1.f / (1.f + __expf(-g));
                    float v = g * sig * u * sPw[rr];
                    int col = n0 + wc * 64 + nf * 16 + frow;
                    Hbuf[(size_t)(row0 + rr) * I_DIM + col] = f2bf(v);
                }
            }
}

__global__ __launch_bounds__(256, 2) void gemm2_kernel(
    const short* __restrict__ Hbuf, const float* __restrict__ Wo,
    const int* __restrict__ pair_token,
    const int* __restrict__ tile_expert, const int* __restrict__ tile_row0,
    const int* __restrict__ tile_rows,
    float* __restrict__ out)
{
    const int tile = blockIdx.x;
    const int rows = tile_rows[tile];
    if (rows == 0) return;
    const int e    = tile_expert[tile];
    const int row0 = tile_row0[tile];
    const int n0   = blockIdx.y * 256;

    __shared__ short sA[BM][BK + 8];
    __shared__ short sB[256][BK + 8];
    __shared__ int   sTok[BM];

    const int tid = threadIdx.x;
    if (tid < BM) sTok[tid] = pair_token[row0 + min(tid, rows - 1)];
    __syncthreads();

    const int srow  = tid >> 1;
    const int shalf = tid & 1;

    const short* aptr = Hbuf + (size_t)(row0 + min(srow, rows - 1)) * I_DIM + shalf * 16;
    const float* bptrA = Wo + ((size_t)e * H_DIM + (n0 + srow))       * I_DIM + shalf * 16;
    const float* bptrB = Wo + ((size_t)e * H_DIM + (n0 + srow + 128)) * I_DIM + shalf * 16;

    bf16x8 ra[2];
    f32x4v rbA[4], rbB[4];
    f32x4v acc[4][8];
    #pragma unroll
    for (int mf = 0; mf < 4; ++mf)
        #pragma unroll
        for (int nf = 0; nf < 8; ++nf) acc[mf][nf] = (f32x4v)0.f;

    const int lane = tid & 63;
    const int wid  = tid >> 6;
    const int wr   = wid >> 1;
    const int wc   = wid & 1;
    const int frow = lane & 15;
    const int fk   = (lane >> 4) * 8;

    ra[0] = *(const bf16x8*)(aptr);
    ra[1] = *(const bf16x8*)(aptr + 8);
    #pragma unroll
    for (int i = 0; i < 4; ++i) { rbA[i] = *(const f32x4v*)(bptrA + i * 4); rbB[i] = *(const f32x4v*)(bptrB + i * 4); }

    const int KT = I_DIM / BK;
    for (int kt = 0; kt < KT; ++kt) {
        __syncthreads();
        *(bf16x8*)&sA[srow][shalf * 16]           = ra[0];
        *(bf16x8*)&sA[srow][shalf * 16 + 8]       = ra[1];
        *(bf16x8*)&sB[srow][shalf * 16]           = pack8(rbA[0], rbA[1]);
        *(bf16x8*)&sB[srow][shalf * 16 + 8]       = pack8(rbA[2], rbA[3]);
        *(bf16x8*)&sB[srow + 128][shalf * 16]     = pack8(rbB[0], rbB[1]);
        *(bf16x8*)&sB[srow + 128][shalf * 16 + 8] = pack8(rbB[2], rbB[3]);
        __syncthreads();

        if (kt + 1 < KT) {
            const int k = (kt + 1) * BK;
            ra[0] = *(const bf16x8*)(aptr + k);
            ra[1] = *(const bf16x8*)(aptr + k + 8);
            #pragma unroll
            for (int i = 0; i < 4; ++i) { rbA[i] = *(const f32x4v*)(bptrA + k + i * 4); rbB[i] = *(const f32x4v*)(bptrB + k + i * 4); }
        }

        bf16x8 af[4];
        #pragma unroll
        for (int mf = 0; mf < 4; ++mf)
            af[mf] = *(const bf16x8*)&sA[wr * 64 + mf * 16 + frow][fk];
        #pragma unroll
        for (int nf = 0; nf < 8; ++nf) {
            bf16x8 bfv = *(const bf16x8*)&sB[wc * 128 + nf * 16 + frow][fk];
            #pragma unroll
            for (int mf = 0; mf < 4; ++mf)
                acc[mf][nf] = __builtin_amdgcn_mfma_f32_16x16x32_bf16(af[mf], bfv, acc[mf][nf], 0, 0, 0);
        }
    }

    const int r4 = (lane >> 4) * 4;
    #pragma unroll
    for (int mf = 0; mf < 4; ++mf)
        #pragma unroll
        for (int nf = 0; nf < 8; ++nf)
            #pragma unroll
            for (int j = 0; j < 4; ++j) {
                int rr = wr * 64 + mf * 16 + r4 + j;
                if (rr < rows) {
                    int col = n0 + wc * 128 + nf * 16 + (lane & 15);
                    atomicAdd(out + (size_t)sTok[rr] * H_DIM + col, acc[mf][nf][j]);
                }
            }
}

// ---------------- launch ----------------
extern "C" void kernel_launch(void* const* d_in, const int* in_sizes, int n_in,
                              void* d_out, int out_size, void* d_ws, size_t ws_size,
                              hipStream_t stream)
{
    (void)in_sizes; (void)n_in;
    const float* X     = (const float*)d_in[0];
    const float* topw  = (const float*)d_in[1];
    const int*   topid = (const int*)d_in[2];
    const float* Wi0   = (const float*)d_in[3];
    const float* Wi1   = (const float*)d_in[4];
    const float* Wo    = (const float*)d_in[5];
    float* out = (float*)d_out;

    char* ws = (char*)d_ws;
    int*   pair_token  = (int*)ws;
    float* pair_w      = (float*)(ws + NPAIR * 4);
    int*   tile_expert = (int*)(ws + NPAIR * 8);
    int*   tile_row0   = tile_expert + MAXT;
    int*   tile_rows   = tile_row0 + MAXT;
    int*   t1_expert   = tile_rows + MAXT;
    int*   t1_row0     = t1_expert + MAXT1;
    int*   t1_rows     = t1_row0 + MAXT1;

    route_kernel<<<1, 256, 0, stream>>>(topid, topw, pair_token, pair_w,
                                        tile_expert, tile_row0, tile_rows,
                                        t1_expert, t1_row0, t1_rows);

    if (ws_size >= NEED_NEW) {
        short* Ht  = (short*)(ws + HT_OFF);
        short* Wot = (short*)(ws + W0_OFF);
        short* At  = (short*)(ws + AT_OFF);

        hipMemsetAsync(d_out, 0, (size_t)out_size * sizeof(float), stream);

        aprep_kernel<<<2560, 256, 0, stream>>>(X, pair_token, t1_row0, t1_rows, At);

        gemm1b_kernel<<<MAXT1 * 16, 512, 0, stream>>>(
            At, Wi0, Wi1, pair_w, t1_expert, t1_row0, t1_rows, Ht);

        woprep_kernel<<<4096, 256, 0, stream>>>(Wo, Wot);

        gemm2b_kernel<<<MAXT1 * 16, 512, 0, stream>>>(
            Ht, Wot, pair_token, t1_expert, t1_row0, t1_rows, out);
    } else {
        short* Hbuf = (short*)(ws + (1 << 20));
        short* Xbf  = (short*)d_out;

        cvt_kernel<<<T_TOK * H_DIM / (256 * 8), 256, 0, stream>>>(X, Xbf);

        gemm1_kernel<<<dim3(MAXT1, I_DIM / BN1), 512, 0, stream>>>(
            Xbf, Wi0, Wi1, pair_token, pair_w, t1_expert, t1_row0, t1_rows, Hbuf);

        hipMemsetAsync(d_out, 0, (size_t)out_size * sizeof(float), stream);

        gemm2_kernel<<<dim3(MAXT, H_DIM / 256), 256, 0, stream>>>(
            Hbuf, Wo, pair_token, tile_expert, tile_row0, tile_rows, out);
    }
}

// Round 10
// 1009.663 us; speedup vs baseline: 1.1865x; 1.1865x over previous
//
#include <hip/hip_runtime.h>
#include <hip/hip_bf16.h>

#define T_TOK 4096
#define H_DIM 4096
#define I_DIM 2048
#define N_EXP 8
#define TOPK  2
#define NPAIR (T_TOK*TOPK)          // 8192
#define BM    128                   // BM=128 tiling (gemm1s + fallback gemm2)
#define BK    32
#define MAXT  (NPAIR/BM + N_EXP)    // 72
#define BM1   256
#define BN1   128
#define MAXT1 (NPAIR/BM1 + N_EXP)   // 40

// ---- workspace offsets (bytes) ----
#define HT_OFF   ((size_t)1 << 20)                  // Ht: 40MB
#define W0_OFF   ((size_t)44 << 20)                 // Wot: 134MB (written AFTER gemm1s; overlays At128/Ws)
#define AT_OFF   ((size_t)44 << 20)                 // At128: 72MB (dead after gemm1s)
#define WS_OFF   ((size_t)120 << 20)                // Ws stacked bf16: 268MB (dead after gemm1s)
#define NEED_NEW (WS_OFF + 268435456ull)            // ~376 MiB  (ws >= 438MB proven in R4)

typedef __attribute__((ext_vector_type(8))) short  bf16x8;
typedef __attribute__((ext_vector_type(4))) float  f32x4v;

__device__ __forceinline__ short f2bf(float f) {
    __hip_bfloat16 h = __float2bfloat16(f);
    return __builtin_bit_cast(short, h);
}
__device__ __forceinline__ float bf2f(short s) {
    unsigned int u = ((unsigned int)(unsigned short)s) << 16;
    return __builtin_bit_cast(float, u);
}

__device__ __forceinline__ bf16x8 pack8(f32x4v a, f32x4v b) {
    bf16x8 r;
    r[0]=f2bf(a[0]); r[1]=f2bf(a[1]); r[2]=f2bf(a[2]); r[3]=f2bf(a[3]);
    r[4]=f2bf(b[0]); r[5]=f2bf(b[1]); r[6]=f2bf(b[2]); r[7]=f2bf(b[3]);
    return r;
}

__device__ __forceinline__ void load_lds16(const short* g, short* l) {
    __builtin_amdgcn_global_load_lds(
        (const __attribute__((address_space(1))) void*)g,
        (__attribute__((address_space(3))) void*)l, 16, 0, 0);
}

// ---------------- fp32 -> bf16 plain (fallback X path) ----------------
__global__ void cvt_kernel(const float* __restrict__ X, short* __restrict__ Xbf) {
    const size_t i = ((size_t)blockIdx.x * 256 + threadIdx.x) * 8;
    f32x4v a = *(const f32x4v*)(X + i);
    f32x4v b = *(const f32x4v*)(X + i + 4);
    *(bf16x8*)(Xbf + i) = pack8(a, b);
}

// ---------------- routing ----------------
__global__ void route_kernel(const int* __restrict__ ids, const float* __restrict__ wts,
                             int* __restrict__ pair_token, float* __restrict__ pair_w,
                             int* __restrict__ tile_expert, int* __restrict__ tile_row0,
                             int* __restrict__ tile_rows,
                             int* __restrict__ t1_expert, int* __restrict__ t1_row0,
                             int* __restrict__ t1_rows)
{
    __shared__ int scn[256][N_EXP];
    const int tid = threadIdx.x;
    const int PPT = NPAIR / 256;
    const int base = tid * PPT;

    int c[N_EXP], orig[N_EXP];
    #pragma unroll
    for (int e = 0; e < N_EXP; ++e) c[e] = 0;
    for (int p = 0; p < PPT; ++p) c[ids[base + p]]++;
    #pragma unroll
    for (int e = 0; e < N_EXP; ++e) { orig[e] = c[e]; scn[tid][e] = c[e]; }
    __syncthreads();

    for (int off = 1; off < 256; off <<= 1) {
        int add[N_EXP];
        #pragma unroll
        for (int e = 0; e < N_EXP; ++e) add[e] = (tid >= off) ? scn[tid - off][e] : 0;
        __syncthreads();
        #pragma unroll
        for (int e = 0; e < N_EXP; ++e) { c[e] += add[e]; scn[tid][e] = c[e]; }
        __syncthreads();
    }

    int segs[N_EXP + 1];
    {
        int run = 0;
        #pragma unroll
        for (int e = 0; e < N_EXP; ++e) { segs[e] = run; run += scn[255][e]; }
        segs[N_EXP] = run;
    }
    int pos[N_EXP];
    #pragma unroll
    for (int e = 0; e < N_EXP; ++e) pos[e] = segs[e] + c[e] - orig[e];

    for (int p = 0; p < PPT; ++p) {
        int pp = base + p;
        int e = ids[pp];
        int q = pos[e]++;
        pair_token[q] = pp / TOPK;
        pair_w[q]     = wts[pp];
    }

    if (tid == 0) {
        int t = 0;
        for (int e = 0; e < N_EXP; ++e) {
            int s = segs[e], en = segs[e + 1];
            for (int r = s; r < en; r += BM) {
                tile_expert[t] = e; tile_row0[t] = r; tile_rows[t] = min(BM, en - r); ++t;
            }
        }
        for (; t < MAXT; ++t) { tile_expert[t] = 0; tile_row0[t] = 0; tile_rows[t] = 0; }

        t = 0;
        for (int e = 0; e < N_EXP; ++e) {
            int s = segs[e], en = segs[e + 1];
            for (int r = s; r < en; r += BM1) {
                t1_expert[t] = e; t1_row0[t] = r; t1_rows[t] = min(BM1, en - r); ++t;
            }
        }
        for (; t < MAXT1; ++t) { t1_expert[t] = 0; t1_row0[t] = 0; t1_rows[t] = 0; }
    }
}

// ================= coalesced LDS-transpose preps =================
#define PRP 132

// Stacked Wi -> Ws [e][nt 32][kt 64][q 8][r 128][x 8]   (nt<16: Wi0, else Wi1)
__global__ __launch_bounds__(256) void wsprep_kernel(const float* __restrict__ Wi0,
                                                     const float* __restrict__ Wi1,
                                                     short* __restrict__ Ws) {
    const int bid = blockIdx.x;          // 8 * 32 * 32 = 8192
    const int e   = bid >> 10;
    const int nt  = (bid >> 5) & 31;
    const int ktg = bid & 31;
    __shared__ short lds[128][PRP];
    const int tid = threadIdx.x;
    const float* W = (nt < 16) ? Wi0 : Wi1;
    const int jr0  = (nt & 15) * 128;
    const float* src0 = W + ((size_t)e * 2048 + jr0) * 4096 + ktg * 128;
    #pragma unroll
    for (int it = 0; it < 8; ++it) {
        int r  = it * 16 + (tid >> 4);
        int hc = (tid & 15) * 8;
        const float* s = src0 + (size_t)r * 4096 + hc;
        f32x4v a = *(const f32x4v*)s;
        f32x4v b = *(const f32x4v*)(s + 4);
        *(bf16x8*)&lds[r][hc] = pack8(a, b);
    }
    __syncthreads();
    short* dst = Ws + ((size_t)(e * 32 + nt)) * 524288 + (size_t)ktg * 2 * 8192;
    #pragma unroll
    for (int it = 0; it < 8; ++it) {
        int idx = it * 256 + tid;        // 0..2047
        int c8  = idx >> 7;              // 0..15
        int r   = idx & 127;
        bf16x8 v = *(const bf16x8*)&lds[r][c8 * 8];
        *(bf16x8*)(dst + (size_t)(c8 >> 3) * 8192 + (c8 & 7) * 1024 + r * 8) = v;
    }
}

// X gather -> At128 [tile 72][kt 64][q 8][r 128][x 8]
__global__ __launch_bounds__(256) void aprep128_kernel(const float* __restrict__ X,
                             const int* __restrict__ pair_token,
                             const int* __restrict__ tile_row0, const int* __restrict__ tile_rows,
                             short* __restrict__ At) {
    const int bid  = blockIdx.x;         // 72 * 32 = 2304
    const int tile = bid >> 5;
    const int ktg  = bid & 31;
    const int rows = tile_rows[tile];
    if (rows == 0) return;
    const int row0 = tile_row0[tile];
    __shared__ short lds[128][PRP];
    const int tid = threadIdx.x;
    #pragma unroll
    for (int it = 0; it < 8; ++it) {
        int r  = it * 16 + (tid >> 4);
        int hc = (tid & 15) * 8;
        int tok = pair_token[row0 + min(r, rows - 1)];
        const float* s = X + (size_t)tok * 4096 + ktg * 128 + hc;
        f32x4v a = *(const f32x4v*)s;
        f32x4v b = *(const f32x4v*)(s + 4);
        *(bf16x8*)&lds[r][hc] = pack8(a, b);
    }
    __syncthreads();
    short* dst = At + (size_t)tile * 524288 + (size_t)ktg * 2 * 8192;
    #pragma unroll
    for (int it = 0; it < 8; ++it) {
        int idx = it * 256 + tid;
        int c8  = idx >> 7;
        int r   = idx & 127;
        bf16x8 v = *(const bf16x8*)&lds[r][c8 * 8];
        *(bf16x8*)(dst + (size_t)(c8 >> 3) * 8192 + (c8 & 7) * 1024 + r * 8) = v;
    }
}

// Wo (E,H,I) fp32 -> Wot [e][hb][kt 64][q 4][r 256][x 8]  (unchanged)
__global__ __launch_bounds__(256) void woprep_kernel(const float* __restrict__ W, short* __restrict__ Wt) {
    const int bid = blockIdx.x;          // 4096
    const int e   = bid >> 9;
    const int hb  = (bid >> 5) & 15;
    const int rh  = (bid >> 4) & 1;
    const int ktg = bid & 15;
    __shared__ short lds[128][PRP];
    const int tid = threadIdx.x;
    const float* src0 = W + ((size_t)(e * 4096 + hb * 256 + rh * 128)) * 2048 + ktg * 128;
    #pragma unroll
    for (int it = 0; it < 8; ++it) {
        int r  = it * 16 + (tid >> 4);
        int hc = (tid & 15) * 8;
        const float* s = src0 + (size_t)r * 2048 + hc;
        f32x4v a = *(const f32x4v*)s;
        f32x4v b = *(const f32x4v*)(s + 4);
        *(bf16x8*)&lds[r][hc] = pack8(a, b);
    }
    __syncthreads();
    short* dst = Wt + (((size_t)(e * 16 + hb) * 64 + ktg * 4) * 8192) + rh * 1024;
    #pragma unroll
    for (int it = 0; it < 8; ++it) {
        int off = it * 2048 + tid * 8;
        int ktl = off >> 12;
        int q   = (off >> 10) & 3;
        int rl  = (off >> 3) & 127;
        bf16x8 v = *(const bf16x8*)&lds[rl][ktl * 32 + q * 8];
        *(bf16x8*)(dst + (size_t)ktl * 8192 + q * 2048 + rl * 8) = v;
    }
}

// ================= GEMM1s: stacked single-mat, 128x128 tile, BK=64, m97-style =================
// LDS (16B slots): A [0..1023] = c*128 + r ; B [1024..2047] = 1024 + c*128 + r   (c = k-chunk 0..7)
__global__ __launch_bounds__(256, 3) void gemm1s_kernel(
    const short* __restrict__ At,       // [72][64][8][128][8]
    const short* __restrict__ Ws,       // [E][32][64][8][128][8]
    const int* __restrict__ tile_expert, const int* __restrict__ tile_row0,
    const int* __restrict__ tile_rows,
    short* __restrict__ GU)             // [NPAIR][4096] raw gate|up
{
    const int b   = blockIdx.x;          // 2304 = 72*32
    const int l   = (b & 7) * 288 + (b >> 3);
    const int tile  = l >> 5;
    const int n0idx = l & 31;            // stacked-col slice of 128
    const int rows = tile_rows[tile];
    if (rows == 0) return;
    const int e    = tile_expert[tile];
    const int row0 = tile_row0[tile];

    __shared__ short sAB[2048 * 8];      // 32 KB

    const int tid  = threadIdx.x;
    const int lane = tid & 63;
    const int w    = tid >> 6;           // 0..3

    const short* aT = At + (size_t)tile * 524288;
    const short* bT = Ws + ((size_t)e * 32 + n0idx) * 524288;

    const int wr = w >> 1, wc = w & 1;   // wave 64x64 quadrant
    const int frow = lane & 15, fsel = lane >> 4;

    f32x4v acc[4][4];
    #pragma unroll
    for (int mf = 0; mf < 4; ++mf)
        #pragma unroll
        for (int nf = 0; nf < 4; ++nf) acc[mf][nf] = (f32x4v)0.f;

    const int KT = H_DIM / 64;           // 64
    for (int kt = 0; kt < KT; ++kt) {
        __syncthreads();                 // prev compute done; safe to overwrite
        {
            const size_t ko = (size_t)kt * 8192;
            #pragma unroll
            for (int i = 0; i < 4; ++i) {
                load_lds16(aT + ko + (size_t)tid * 8 + i * 2048,
                           &sAB[(i * 256 + w * 64) * 8]);
                load_lds16(bT + ko + (size_t)tid * 8 + i * 2048,
                           &sAB[((1024 + i * 256 + w * 64)) * 8]);
            }
        }
        __syncthreads();                 // compiler drains vmcnt before barrier

        #pragma unroll
        for (int h = 0; h < 2; ++h) {
            const int c = h * 4 + fsel;
            bf16x8 af[4];
            #pragma unroll
            for (int mf = 0; mf < 4; ++mf)
                af[mf] = *(const bf16x8*)&sAB[(c * 128 + wr * 64 + mf * 16 + frow) * 8];
            #pragma unroll
            for (int nf = 0; nf < 4; ++nf) {
                bf16x8 bf = *(const bf16x8*)&sAB[(1024 + c * 128 + wc * 64 + nf * 16 + frow) * 8];
                #pragma unroll
                for (int mf = 0; mf < 4; ++mf)
                    acc[mf][nf] = __builtin_amdgcn_mfma_f32_16x16x32_bf16(af[mf], bf, acc[mf][nf], 0, 0, 0);
            }
        }
    }

    // epilogue: raw bf16 GU write
    const int r4 = fsel * 4;
    #pragma unroll
    for (int mf = 0; mf < 4; ++mf)
        #pragma unroll
        for (int nf = 0; nf < 4; ++nf) {
            const int col = n0idx * 128 + wc * 64 + nf * 16 + frow;
            #pragma unroll
            for (int j = 0; j < 4; ++j) {
                int rr = wr * 64 + mf * 16 + r4 + j;
                if (rr < rows)
                    GU[(size_t)(row0 + rr) * 4096 + col] = f2bf(acc[mf][nf][j]);
            }
        }
}

// ================= act: h = silu(g)*u*pw -> Ht tiled =================
__global__ __launch_bounds__(256) void act_kernel(
    const short* __restrict__ GU,        // [NPAIR][4096]
    const float* __restrict__ pair_w,
    const int* __restrict__ t1_row0, const int* __restrict__ t1_rows,
    short* __restrict__ Ht)              // [40][64][4][256][8]
{
    const int bid  = blockIdx.x;         // 40*256
    const int tile = bid >> 8;
    const int r    = bid & 255;
    const int rows = t1_rows[tile];
    if (r >= rows) return;
    const int p    = t1_row0[tile] + r;
    const float pw = pair_w[p];
    const int tid  = threadIdx.x;        // col chunk = tid*8

    const short* g8p = GU + (size_t)p * 4096 + tid * 8;
    bf16x8 g8 = *(const bf16x8*)g8p;
    bf16x8 u8 = *(const bf16x8*)(g8p + 2048);
    bf16x8 o;
    #pragma unroll
    for (int k = 0; k < 8; ++k) {
        float g = bf2f(g8[k]);
        float u = bf2f(u8[k]);
        float sig = 1.f / (1.f + __expf(-g));
        o[k] = f2bf(g * sig * u * pw);
    }
    const int c = tid * 8;
    *(bf16x8*)(Ht + (size_t)tile * 524288 + (size_t)(c >> 5) * 8192
               + ((c >> 3) & 3) * 2048 + r * 8) = o;
}

// ================= GEMM2 (UNCHANGED — control) =================
__global__ __launch_bounds__(512, 2) void gemm2b_kernel(
    const short* __restrict__ Ht,
    const short* __restrict__ Wot,
    const int* __restrict__ pair_token,
    const int* __restrict__ t1_expert, const int* __restrict__ t1_row0,
    const int* __restrict__ t1_rows,
    float* __restrict__ out)
{
    const int b    = blockIdx.x;
    const int xcd  = b & 7;
    const int i    = b >> 3;
    const int tile  = xcd * 5 + (i >> 4);
    const int n0idx = i & 15;
    const int rows = t1_rows[tile];
    if (rows == 0) return;
    const int e    = t1_expert[tile];
    const int row0 = t1_row0[tile];
    const int n0   = n0idx * 256;

    __shared__ short stg[4][16384];
    __shared__ int   sTok[BM1];

    const int tid  = threadIdx.x;
    const int lane = tid & 63;
    const int w    = tid >> 6;
    const int wof  = w * 512;

    if (tid < BM1) sTok[tid] = pair_token[row0 + min(tid, rows - 1)];
    __syncthreads();

    const short* aT = Ht  + (size_t)tile * 524288 + (size_t)tid * 8;
    const short* bT = Wot + ((size_t)e * 16 + n0idx) * 524288 + (size_t)tid * 8;

    const int wr = w >> 1, wc = w & 1;
    const int frow = lane & 15, fsel = lane >> 4;

    f32x4v acc[4][8];
    #pragma unroll
    for (int mf = 0; mf < 4; ++mf)
        #pragma unroll
        for (int nf = 0; nf < 8; ++nf) acc[mf][nf] = (f32x4v)0.f;

#define STAGE2(s, kt) do { \
        short* st_ = &stg[s][0] + wof; \
        const size_t ko_ = (size_t)(kt); \
        load_lds16(aT + ko_ * 8192,        st_); \
        load_lds16(aT + ko_ * 8192 + 4096, st_ + 4096); \
        load_lds16(bT + ko_ * 8192,        st_ + 8192); \
        load_lds16(bT + ko_ * 8192 + 4096, st_ + 12288); \
    } while (0)

#define COMPUTE2(s) do { \
        const short* st_ = &stg[s][0]; \
        bf16x8 af[4], bf_[8]; \
        _Pragma("unroll") \
        for (int mf = 0; mf < 4; ++mf) \
            af[mf] = *(const bf16x8*)(st_ + (fsel * 256 + wr * 64 + mf * 16 + frow) * 8); \
        _Pragma("unroll") \
        for (int nf = 0; nf < 8; ++nf) \
            bf_[nf] = *(const bf16x8*)(st_ + (1024 + fsel * 256 + wc * 128 + nf * 16 + frow) * 8); \
        __builtin_amdgcn_s_setprio(1); \
        _Pragma("unroll") \
        for (int nf = 0; nf < 8; ++nf) \
            _Pragma("unroll") \
            for (int mf = 0; mf < 4; ++mf) \
                acc[mf][nf] = __builtin_amdgcn_mfma_f32_16x16x32_bf16(af[mf], bf_[nf], acc[mf][nf], 0, 0, 0); \
        __builtin_amdgcn_s_setprio(0); \
    } while (0)

    STAGE2(0, 0); STAGE2(1, 1); STAGE2(2, 2);
    asm volatile("s_waitcnt vmcnt(8)" ::: "memory");
    __builtin_amdgcn_s_barrier();
    __builtin_amdgcn_sched_barrier(0);

    const int KT = I_DIM / 32;   // 64
    for (int kt = 0; kt < KT; ++kt) {
        const int cur = kt & 3;
        if (kt + 3 < KT) STAGE2((kt + 3) & 3, kt + 3);
        COMPUTE2(cur);
        if (kt + 1 < KT) {
            __builtin_amdgcn_sched_barrier(0);
            if (kt + 3 < KT)      asm volatile("s_waitcnt vmcnt(8)" ::: "memory");
            else if (kt + 2 < KT) asm volatile("s_waitcnt vmcnt(4)" ::: "memory");
            else                  asm volatile("s_waitcnt vmcnt(0)" ::: "memory");
            __builtin_amdgcn_s_barrier();
            __builtin_amdgcn_sched_barrier(0);
        }
    }
#undef STAGE2
#undef COMPUTE2

    const int r4 = fsel * 4;
    #pragma unroll
    for (int mf = 0; mf < 4; ++mf)
        #pragma unroll
        for (int nf = 0; nf < 8; ++nf)
            #pragma unroll
            for (int j = 0; j < 4; ++j) {
                int rr = wr * 64 + mf * 16 + r4 + j;
                if (rr < rows) {
                    int col = n0 + wc * 128 + nf * 16 + frow;
                    atomicAdd(out + (size_t)sTok[rr] * H_DIM + col, acc[mf][nf][j]);
                }
            }
}

// ================= FALLBACK PATH (R3) =================
__global__ __launch_bounds__(512, 2) void gemm1_kernel(
    const short* __restrict__ Xbf, const float* __restrict__ Wi0, const float* __restrict__ Wi1,
    const int* __restrict__ pair_token, const float* __restrict__ pair_w,
    const int* __restrict__ t1_expert, const int* __restrict__ t1_row0, const int* __restrict__ t1_rows,
    short* __restrict__ Hbuf)
{
    const int tile = blockIdx.x;
    const int rows = t1_rows[tile];
    if (rows == 0) return;
    const int e    = t1_expert[tile];
    const int row0 = t1_row0[tile];
    const int n0   = blockIdx.y * BN1;

    __shared__ short sA [2][BM1][64];
    __shared__ short sB0[2][BN1][64 + 8];
    __shared__ short sB1[2][BN1][64 + 8];
    __shared__ int   sTok[BM1];
    __shared__ float sPw [BM1];

    const int tid  = threadIdx.x;
    const int lane = tid & 63;
    const int w    = tid >> 6;

    if (tid < BM1) {
        int tr = min(tid, rows - 1);
        sTok[tid] = pair_token[row0 + tr];
        sPw[tid]  = (tid < rows) ? pair_w[row0 + tid] : 0.f;
    }
    __syncthreads();

    const short* aSrc[4];
    #pragma unroll
    for (int i = 0; i < 4; ++i) {
        int r = w * 32 + i * 8 + (lane >> 3);
        int j = lane & 7;
        aSrc[i] = Xbf + (size_t)sTok[r] * H_DIM + ((j ^ (r & 7)) * 8);
    }

    const int brow = tid >> 2;
    const int bq   = tid & 3;
    const size_t wboff = ((size_t)e * I_DIM + (n0 + brow)) * H_DIM + bq * 16;
    const float* b0p = Wi0 + wboff;
    const float* b1p = Wi1 + wboff;

    const int wr   = w >> 1;
    const int wc   = w & 1;
    const int frow = lane & 15;
    const int fsel = lane >> 4;

    f32x4v accg[4][4], accu[4][4];
    #pragma unroll
    for (int mf = 0; mf < 4; ++mf)
        #pragma unroll
        for (int nf = 0; nf < 4; ++nf) { accg[mf][nf] = (f32x4v)0.f; accu[mf][nf] = (f32x4v)0.f; }

    f32x4v rb0[4], rb1[4];

    #pragma unroll
    for (int i = 0; i < 4; ++i)
        load_lds16(aSrc[i], &sA[0][w * 32 + i * 8][0]);
    #pragma unroll
    for (int i = 0; i < 4; ++i) { rb0[i] = *(const f32x4v*)(b0p + i * 4); rb1[i] = *(const f32x4v*)(b1p + i * 4); }
    {
        short* d0 = &sB0[0][brow][bq * 16];
        *(bf16x8*)d0       = pack8(rb0[0], rb0[1]);
        *(bf16x8*)(d0 + 8) = pack8(rb0[2], rb0[3]);
        short* d1 = &sB1[0][brow][bq * 16];
        *(bf16x8*)d1       = pack8(rb1[0], rb1[1]);
        *(bf16x8*)(d1 + 8) = pack8(rb1[2], rb1[3]);
    }
    __syncthreads();

    const int KT = H_DIM / 64;
    for (int kt = 0; kt < KT; ++kt) {
        const int cur = kt & 1, nxt = cur ^ 1;
        if (kt + 1 < KT) {
            #pragma unroll
            for (int i = 0; i < 4; ++i)
                load_lds16(aSrc[i] + (kt + 1) * 64, &sA[nxt][w * 32 + i * 8][0]);
            const float* p0 = b0p + (kt + 1) * 64;
            const float* p1 = b1p + (kt + 1) * 64;
            #pragma unroll
            for (int i = 0; i < 4; ++i) { rb0[i] = *(const f32x4v*)(p0 + i * 4); rb1[i] = *(const f32x4v*)(p1 + i * 4); }
        }
        #pragma unroll
        for (int h = 0; h < 2; ++h) {
            bf16x8 af[4], b0f[4], b1f[4];
            #pragma unroll
            for (int mf = 0; mf < 4; ++mf) {
                int ar = wr * 64 + mf * 16 + frow;
                int c  = (h * 4 + fsel) ^ (ar & 7);
                af[mf] = *(const bf16x8*)((const char*)&sA[cur][0][0] + ar * 128 + c * 16);
            }
            #pragma unroll
            for (int nf = 0; nf < 4; ++nf) {
                int br = wc * 64 + nf * 16 + frow;
                b0f[nf] = *(const bf16x8*)&sB0[cur][br][h * 32 + fsel * 8];
                b1f[nf] = *(const bf16x8*)&sB1[cur][br][h * 32 + fsel * 8];
            }
            #pragma unroll
            for (int nf = 0; nf < 4; ++nf)
                #pragma unroll
                for (int mf = 0; mf < 4; ++mf) {
                    accg[mf][nf] = __builtin_amdgcn_mfma_f32_16x16x32_bf16(af[mf], b0f[nf], accg[mf][nf], 0, 0, 0);
                    accu[mf][nf] = __builtin_amdgcn_mfma_f32_16x16x32_bf16(af[mf], b1f[nf], accu[mf][nf], 0, 0, 0);
                }
        }
        if (kt + 1 < KT) {
            short* d0 = &sB0[nxt][brow][bq * 16];
            *(bf16x8*)d0       = pack8(rb0[0], rb0[1]);
            *(bf16x8*)(d0 + 8) = pack8(rb0[2], rb0[3]);
            short* d1 = &sB1[nxt][brow][bq * 16];
            *(bf16x8*)d1       = pack8(rb1[0], rb1[1]);
            *(bf16x8*)(d1 + 8) = pack8(rb1[2], rb1[3]);
        }
        __syncthreads();
    }

    const int r4 = fsel * 4;
    #pragma unroll
    for (int mf = 0; mf < 4; ++mf)
        #pragma unroll
        for (int nf = 0; nf < 4; ++nf)
            #pragma unroll
            for (int j = 0; j < 4; ++j) {
                int rr = wr * 64 + mf * 16 + r4 + j;
                if (rr < rows) {
                    float g = accg[mf][nf][j];
                    float u = accu[mf][nf][j];
                    float sig = 1.f / (1.f + __expf(-g));
                    float v = g * sig * u * sPw[rr];
                    int col = n0 + wc * 64 + nf * 16 + frow;
                    Hbuf[(size_t)(row0 + rr) * I_DIM + col] = f2bf(v);
                }
            }
}

__global__ __launch_bounds__(256, 2) void gemm2_kernel(
    const short* __restrict__ Hbuf, const float* __restrict__ Wo,
    const int* __restrict__ pair_token,
    const int* __restrict__ tile_expert, const int* __restrict__ tile_row0,
    const int* __restrict__ tile_rows,
    float* __restrict__ out)
{
    const int tile = blockIdx.x;
    const int rows = tile_rows[tile];
    if (rows == 0) return;
    const int e    = tile_expert[tile];
    const int row0 = tile_row0[tile];
    const int n0   = blockIdx.y * 256;

    __shared__ short sA[BM][BK + 8];
    __shared__ short sB[256][BK + 8];
    __shared__ int   sTok[BM];

    const int tid = threadIdx.x;
    if (tid < BM) sTok[tid] = pair_token[row0 + min(tid, rows - 1)];
    __syncthreads();

    const int srow  = tid >> 1;
    const int shalf = tid & 1;

    const short* aptr = Hbuf + (size_t)(row0 + min(srow, rows - 1)) * I_DIM + shalf * 16;
    const float* bptrA = Wo + ((size_t)e * H_DIM + (n0 + srow))       * I_DIM + shalf * 16;
    const float* bptrB = Wo + ((size_t)e * H_DIM + (n0 + srow + 128)) * I_DIM + shalf * 16;

    bf16x8 ra[2];
    f32x4v rbA[4], rbB[4];
    f32x4v acc[4][8];
    #pragma unroll
    for (int mf = 0; mf < 4; ++mf)
        #pragma unroll
        for (int nf = 0; nf < 8; ++nf) acc[mf][nf] = (f32x4v)0.f;

    const int lane = tid & 63;
    const int wid  = tid >> 6;
    const int wr   = wid >> 1;
    const int wc   = wid & 1;
    const int frow = lane & 15;
    const int fk   = (lane >> 4) * 8;

    ra[0] = *(const bf16x8*)(aptr);
    ra[1] = *(const bf16x8*)(aptr + 8);
    #pragma unroll
    for (int i = 0; i < 4; ++i) { rbA[i] = *(const f32x4v*)(bptrA + i * 4); rbB[i] = *(const f32x4v*)(bptrB + i * 4); }

    const int KT = I_DIM / BK;
    for (int kt = 0; kt < KT; ++kt) {
        __syncthreads();
        *(bf16x8*)&sA[srow][shalf * 16]           = ra[0];
        *(bf16x8*)&sA[srow][shalf * 16 + 8]       = ra[1];
        *(bf16x8*)&sB[srow][shalf * 16]           = pack8(rbA[0], rbA[1]);
        *(bf16x8*)&sB[srow][shalf * 16 + 8]       = pack8(rbA[2], rbA[3]);
        *(bf16x8*)&sB[srow + 128][shalf * 16]     = pack8(rbB[0], rbB[1]);
        *(bf16x8*)&sB[srow + 128][shalf * 16 + 8] = pack8(rbB[2], rbB[3]);
        __syncthreads();

        if (kt + 1 < KT) {
            const int k = (kt + 1) * BK;
            ra[0] = *(const bf16x8*)(aptr + k);
            ra[1] = *(const bf16x8*)(aptr + k + 8);
            #pragma unroll
            for (int i = 0; i < 4; ++i) { rbA[i] = *(const f32x4v*)(bptrA + k + i * 4); rbB[i] = *(const f32x4v*)(bptrB + k + i * 4); }
        }

        bf16x8 af[4];
        #pragma unroll
        for (int mf = 0; mf < 4; ++mf)
            af[mf] = *(const bf16x8*)&sA[wr * 64 + mf * 16 + frow][fk];
        #pragma unroll
        for (int nf = 0; nf < 8; ++nf) {
            bf16x8 bfv = *(const bf16x8*)&sB[wc * 128 + nf * 16 + frow][fk];
            #pragma unroll
            for (int mf = 0; mf < 4; ++mf)
                acc[mf][nf] = __builtin_amdgcn_mfma_f32_16x16x32_bf16(af[mf], bfv, acc[mf][nf], 0, 0, 0);
        }
    }

    const int r4 = (lane >> 4) * 4;
    #pragma unroll
    for (int mf = 0; mf < 4; ++mf)
        #pragma unroll
        for (int nf = 0; nf < 8; ++nf)
            #pragma unroll
            for (int j = 0; j < 4; ++j) {
                int rr = wr * 64 + mf * 16 + r4 + j;
                if (rr < rows) {
                    int col = n0 + wc * 128 + nf * 16 + (lane & 15);
                    atomicAdd(out + (size_t)sTok[rr] * H_DIM + col, acc[mf][nf][j]);
                }
            }
}

// ---------------- launch ----------------
extern "C" void kernel_launch(void* const* d_in, const int* in_sizes, int n_in,
                              void* d_out, int out_size, void* d_ws, size_t ws_size,
                              hipStream_t stream)
{
    (void)in_sizes; (void)n_in;
    const float* X     = (const float*)d_in[0];
    const float* topw  = (const float*)d_in[1];
    const int*   topid = (const int*)d_in[2];
    const float* Wi0   = (const float*)d_in[3];
    const float* Wi1   = (const float*)d_in[4];
    const float* Wo    = (const float*)d_in[5];
    float* out = (float*)d_out;

    char* ws = (char*)d_ws;
    int*   pair_token  = (int*)ws;
    float* pair_w      = (float*)(ws + NPAIR * 4);
    int*   tile_expert = (int*)(ws + NPAIR * 8);
    int*   tile_row0   = tile_expert + MAXT;
    int*   tile_rows   = tile_row0 + MAXT;
    int*   t1_expert   = tile_rows + MAXT;
    int*   t1_row0     = t1_expert + MAXT1;
    int*   t1_rows     = t1_row0 + MAXT1;

    route_kernel<<<1, 256, 0, stream>>>(topid, topw, pair_token, pair_w,
                                        tile_expert, tile_row0, tile_rows,
                                        t1_expert, t1_row0, t1_rows);

    if (ws_size >= NEED_NEW) {
        short* Ht  = (short*)(ws + HT_OFF);
        short* At  = (short*)(ws + AT_OFF);
        short* Ws  = (short*)(ws + WS_OFF);
        short* Wot = (short*)(ws + W0_OFF);   // overlays At/Ws (dead after gemm1s)
        short* GU  = (short*)d_out;           // 67MB scratch, reclaimed by memset

        aprep128_kernel<<<2304, 256, 0, stream>>>(X, pair_token, tile_row0, tile_rows, At);
        wsprep_kernel<<<8192, 256, 0, stream>>>(Wi0, Wi1, Ws);

        gemm1s_kernel<<<2304, 256, 0, stream>>>(
            At, Ws, tile_expert, tile_row0, tile_rows, GU);

        act_kernel<<<MAXT1 * 256, 256, 0, stream>>>(GU, pair_w, t1_row0, t1_rows, Ht);

        hipMemsetAsync(d_out, 0, (size_t)out_size * sizeof(float), stream);

        woprep_kernel<<<4096, 256, 0, stream>>>(Wo, Wot);

        gemm2b_kernel<<<MAXT1 * 16, 512, 0, stream>>>(
            Ht, Wot, pair_token, t1_expert, t1_row0, t1_rows, out);
    } else {
        short* Hbuf = (short*)(ws + (1 << 20));
        short* Xbf  = (short*)d_out;

        cvt_kernel<<<T_TOK * H_DIM / (256 * 8), 256, 0, stream>>>(X, Xbf);

        gemm1_kernel<<<dim3(MAXT1, I_DIM / BN1), 512, 0, stream>>>(
            Xbf, Wi0, Wi1, pair_token, pair_w, t1_expert, t1_row0, t1_rows, Hbuf);

        hipMemsetAsync(d_out, 0, (size_t)out_size * sizeof(float), stream);

        gemm2_kernel<<<dim3(MAXT, H_DIM / 256), 256, 0, stream>>>(
            Hbuf, Wo, pair_token, tile_expert, tile_row0, tile_rows, out);
    }
}

// Round 11
// 884.854 us; speedup vs baseline: 1.3538x; 1.1410x over previous
//
#include <hip/hip_runtime.h>
#include <hip/hip_bf16.h>

#define T_TOK 4096
#define H_DIM 4096
#define I_DIM 2048
#define N_EXP 8
#define TOPK  2
#define NPAIR (T_TOK*TOPK)          // 8192
#define BM    128
#define BK    32
#define MAXT  (NPAIR/BM + N_EXP)    // 72
#define BM1   256
#define BN1   128
#define MAXT1 (NPAIR/BM1 + N_EXP)   // 40

// ---- workspace offsets (bytes) ----
#define HT_OFF   ((size_t)1 << 20)                  // Ht128: 37.7MB
#define W0_OFF   ((size_t)44 << 20)                 // Wot128: 134MB (written AFTER gemm1s)
#define AT_OFF   ((size_t)44 << 20)                 // At128: 72MB (dead after gemm1s)
#define WS_OFF   ((size_t)120 << 20)                // Ws stacked bf16: 268MB (dead after gemm1s)
#define NEED_NEW (WS_OFF + 268435456ull)            // ~376 MiB

typedef __attribute__((ext_vector_type(8))) short  bf16x8;
typedef __attribute__((ext_vector_type(4))) float  f32x4v;

__device__ __forceinline__ short f2bf(float f) {
    __hip_bfloat16 h = __float2bfloat16(f);
    return __builtin_bit_cast(short, h);
}
__device__ __forceinline__ float bf2f(short s) {
    unsigned int u = ((unsigned int)(unsigned short)s) << 16;
    return __builtin_bit_cast(float, u);
}

__device__ __forceinline__ bf16x8 pack8(f32x4v a, f32x4v b) {
    bf16x8 r;
    r[0]=f2bf(a[0]); r[1]=f2bf(a[1]); r[2]=f2bf(a[2]); r[3]=f2bf(a[3]);
    r[4]=f2bf(b[0]); r[5]=f2bf(b[1]); r[6]=f2bf(b[2]); r[7]=f2bf(b[3]);
    return r;
}

__device__ __forceinline__ void load_lds16(const short* g, short* l) {
    __builtin_amdgcn_global_load_lds(
        (const __attribute__((address_space(1))) void*)g,
        (__attribute__((address_space(3))) void*)l, 16, 0, 0);
}

// ---------------- fp32 -> bf16 plain (fallback X path) ----------------
__global__ void cvt_kernel(const float* __restrict__ X, short* __restrict__ Xbf) {
    const size_t i = ((size_t)blockIdx.x * 256 + threadIdx.x) * 8;
    f32x4v a = *(const f32x4v*)(X + i);
    f32x4v b = *(const f32x4v*)(X + i + 4);
    *(bf16x8*)(Xbf + i) = pack8(a, b);
}

// ---------------- routing ----------------
__global__ void route_kernel(const int* __restrict__ ids, const float* __restrict__ wts,
                             int* __restrict__ pair_token, float* __restrict__ pair_w,
                             int* __restrict__ tile_expert, int* __restrict__ tile_row0,
                             int* __restrict__ tile_rows,
                             int* __restrict__ t1_expert, int* __restrict__ t1_row0,
                             int* __restrict__ t1_rows)
{
    __shared__ int scn[256][N_EXP];
    const int tid = threadIdx.x;
    const int PPT = NPAIR / 256;
    const int base = tid * PPT;

    int c[N_EXP], orig[N_EXP];
    #pragma unroll
    for (int e = 0; e < N_EXP; ++e) c[e] = 0;
    for (int p = 0; p < PPT; ++p) c[ids[base + p]]++;
    #pragma unroll
    for (int e = 0; e < N_EXP; ++e) { orig[e] = c[e]; scn[tid][e] = c[e]; }
    __syncthreads();

    for (int off = 1; off < 256; off <<= 1) {
        int add[N_EXP];
        #pragma unroll
        for (int e = 0; e < N_EXP; ++e) add[e] = (tid >= off) ? scn[tid - off][e] : 0;
        __syncthreads();
        #pragma unroll
        for (int e = 0; e < N_EXP; ++e) { c[e] += add[e]; scn[tid][e] = c[e]; }
        __syncthreads();
    }

    int segs[N_EXP + 1];
    {
        int run = 0;
        #pragma unroll
        for (int e = 0; e < N_EXP; ++e) { segs[e] = run; run += scn[255][e]; }
        segs[N_EXP] = run;
    }
    int pos[N_EXP];
    #pragma unroll
    for (int e = 0; e < N_EXP; ++e) pos[e] = segs[e] + c[e] - orig[e];

    for (int p = 0; p < PPT; ++p) {
        int pp = base + p;
        int e = ids[pp];
        int q = pos[e]++;
        pair_token[q] = pp / TOPK;
        pair_w[q]     = wts[pp];
    }

    if (tid == 0) {
        int t = 0;
        for (int e = 0; e < N_EXP; ++e) {
            int s = segs[e], en = segs[e + 1];
            for (int r = s; r < en; r += BM) {
                tile_expert[t] = e; tile_row0[t] = r; tile_rows[t] = min(BM, en - r); ++t;
            }
        }
        for (; t < MAXT; ++t) { tile_expert[t] = 0; tile_row0[t] = 0; tile_rows[t] = 0; }

        t = 0;
        for (int e = 0; e < N_EXP; ++e) {
            int s = segs[e], en = segs[e + 1];
            for (int r = s; r < en; r += BM1) {
                t1_expert[t] = e; t1_row0[t] = r; t1_rows[t] = min(BM1, en - r); ++t;
            }
        }
        for (; t < MAXT1; ++t) { t1_expert[t] = 0; t1_row0[t] = 0; t1_rows[t] = 0; }
    }
}

// ================= coalesced LDS-transpose preps =================
#define PRP 132

// Stacked Wi -> Ws [e][nt 32][kt 64][q 8][r 128][x 8]   (nt<16: Wi0, else Wi1)
__global__ __launch_bounds__(256) void wsprep_kernel(const float* __restrict__ Wi0,
                                                     const float* __restrict__ Wi1,
                                                     short* __restrict__ Ws) {
    const int bid = blockIdx.x;          // 8 * 32 * 32 = 8192
    const int e   = bid >> 10;
    const int nt  = (bid >> 5) & 31;
    const int ktg = bid & 31;
    __shared__ short lds[128][PRP];
    const int tid = threadIdx.x;
    const float* W = (nt < 16) ? Wi0 : Wi1;
    const int jr0  = (nt & 15) * 128;
    const float* src0 = W + ((size_t)e * 2048 + jr0) * 4096 + ktg * 128;
    #pragma unroll
    for (int it = 0; it < 8; ++it) {
        int r  = it * 16 + (tid >> 4);
        int hc = (tid & 15) * 8;
        const float* s = src0 + (size_t)r * 4096 + hc;
        f32x4v a = *(const f32x4v*)s;
        f32x4v b = *(const f32x4v*)(s + 4);
        *(bf16x8*)&lds[r][hc] = pack8(a, b);
    }
    __syncthreads();
    short* dst = Ws + ((size_t)(e * 32 + nt)) * 524288 + (size_t)ktg * 2 * 8192;
    #pragma unroll
    for (int it = 0; it < 8; ++it) {
        int idx = it * 256 + tid;
        int c8  = idx >> 7;
        int r   = idx & 127;
        bf16x8 v = *(const bf16x8*)&lds[r][c8 * 8];
        *(bf16x8*)(dst + (size_t)(c8 >> 3) * 8192 + (c8 & 7) * 1024 + r * 8) = v;
    }
}

// X gather -> At128 [tile 72][kt 64][q 8][r 128][x 8]
__global__ __launch_bounds__(256) void aprep128_kernel(const float* __restrict__ X,
                             const int* __restrict__ pair_token,
                             const int* __restrict__ tile_row0, const int* __restrict__ tile_rows,
                             short* __restrict__ At) {
    const int bid  = blockIdx.x;         // 72 * 32 = 2304
    const int tile = bid >> 5;
    const int ktg  = bid & 31;
    const int rows = tile_rows[tile];
    if (rows == 0) return;
    const int row0 = tile_row0[tile];
    __shared__ short lds[128][PRP];
    const int tid = threadIdx.x;
    #pragma unroll
    for (int it = 0; it < 8; ++it) {
        int r  = it * 16 + (tid >> 4);
        int hc = (tid & 15) * 8;
        int tok = pair_token[row0 + min(r, rows - 1)];
        const float* s = X + (size_t)tok * 4096 + ktg * 128 + hc;
        f32x4v a = *(const f32x4v*)s;
        f32x4v b = *(const f32x4v*)(s + 4);
        *(bf16x8*)&lds[r][hc] = pack8(a, b);
    }
    __syncthreads();
    short* dst = At + (size_t)tile * 524288 + (size_t)ktg * 2 * 8192;
    #pragma unroll
    for (int it = 0; it < 8; ++it) {
        int idx = it * 256 + tid;
        int c8  = idx >> 7;
        int r   = idx & 127;
        bf16x8 v = *(const bf16x8*)&lds[r][c8 * 8];
        *(bf16x8*)(dst + (size_t)(c8 >> 3) * 8192 + (c8 & 7) * 1024 + r * 8) = v;
    }
}

// Wo (E,H,I) fp32 -> Wot128 [e][hb 32][kt 32][q 8][r 128][x 8]
__global__ __launch_bounds__(256) void woprep2_kernel(const float* __restrict__ W, short* __restrict__ Wt) {
    const int bid = blockIdx.x;          // 8 * 32 * 16 = 4096
    const int e   = bid >> 9;
    const int hb  = (bid >> 4) & 31;
    const int ktg = bid & 15;
    __shared__ short lds[128][PRP];
    const int tid = threadIdx.x;
    const float* src0 = W + ((size_t)(e * 4096 + hb * 128)) * 2048 + ktg * 128;
    #pragma unroll
    for (int it = 0; it < 8; ++it) {
        int r  = it * 16 + (tid >> 4);
        int hc = (tid & 15) * 8;
        const float* s = src0 + (size_t)r * 2048 + hc;
        f32x4v a = *(const f32x4v*)s;
        f32x4v b = *(const f32x4v*)(s + 4);
        *(bf16x8*)&lds[r][hc] = pack8(a, b);
    }
    __syncthreads();
    short* dst = Wt + ((size_t)(e * 32 + hb)) * 262144 + (size_t)ktg * 2 * 8192;
    #pragma unroll
    for (int it = 0; it < 8; ++it) {
        int idx = it * 256 + tid;
        int c8  = idx >> 7;
        int r   = idx & 127;
        bf16x8 v = *(const bf16x8*)&lds[r][c8 * 8];
        *(bf16x8*)(dst + (size_t)(c8 >> 3) * 8192 + (c8 & 7) * 1024 + r * 8) = v;
    }
}

// ================= GEMM1s: stacked single-mat, 128x128 tile, BK=64 (proven R10) =================
__global__ __launch_bounds__(256, 3) void gemm1s_kernel(
    const short* __restrict__ At,       // [72][64][8][128][8]
    const short* __restrict__ Ws,       // [E][32][64][8][128][8]
    const int* __restrict__ tile_expert, const int* __restrict__ tile_row0,
    const int* __restrict__ tile_rows,
    short* __restrict__ GU)             // [NPAIR][4096] raw gate|up
{
    const int b   = blockIdx.x;          // 2304 = 72*32
    const int l   = (b & 7) * 288 + (b >> 3);
    const int tile  = l >> 5;
    const int n0idx = l & 31;
    const int rows = tile_rows[tile];
    if (rows == 0) return;
    const int e    = tile_expert[tile];
    const int row0 = tile_row0[tile];

    __shared__ short sAB[2048 * 8];      // 32 KB

    const int tid  = threadIdx.x;
    const int lane = tid & 63;
    const int w    = tid >> 6;

    const short* aT = At + (size_t)tile * 524288;
    const short* bT = Ws + ((size_t)e * 32 + n0idx) * 524288;

    const int wr = w >> 1, wc = w & 1;
    const int frow = lane & 15, fsel = lane >> 4;

    f32x4v acc[4][4];
    #pragma unroll
    for (int mf = 0; mf < 4; ++mf)
        #pragma unroll
        for (int nf = 0; nf < 4; ++nf) acc[mf][nf] = (f32x4v)0.f;

    const int KT = H_DIM / 64;           // 64
    for (int kt = 0; kt < KT; ++kt) {
        __syncthreads();
        {
            const size_t ko = (size_t)kt * 8192;
            #pragma unroll
            for (int i = 0; i < 4; ++i) {
                load_lds16(aT + ko + (size_t)tid * 8 + i * 2048,
                           &sAB[(i * 256 + w * 64) * 8]);
                load_lds16(bT + ko + (size_t)tid * 8 + i * 2048,
                           &sAB[((1024 + i * 256 + w * 64)) * 8]);
            }
        }
        __syncthreads();

        #pragma unroll
        for (int h = 0; h < 2; ++h) {
            const int c = h * 4 + fsel;
            bf16x8 af[4];
            #pragma unroll
            for (int mf = 0; mf < 4; ++mf)
                af[mf] = *(const bf16x8*)&sAB[(c * 128 + wr * 64 + mf * 16 + frow) * 8];
            #pragma unroll
            for (int nf = 0; nf < 4; ++nf) {
                bf16x8 bf = *(const bf16x8*)&sAB[(1024 + c * 128 + wc * 64 + nf * 16 + frow) * 8];
                #pragma unroll
                for (int mf = 0; mf < 4; ++mf)
                    acc[mf][nf] = __builtin_amdgcn_mfma_f32_16x16x32_bf16(af[mf], bf, acc[mf][nf], 0, 0, 0);
            }
        }
    }

    const int r4 = fsel * 4;
    #pragma unroll
    for (int mf = 0; mf < 4; ++mf)
        #pragma unroll
        for (int nf = 0; nf < 4; ++nf) {
            const int col = n0idx * 128 + wc * 64 + nf * 16 + frow;
            #pragma unroll
            for (int j = 0; j < 4; ++j) {
                int rr = wr * 64 + mf * 16 + r4 + j;
                if (rr < rows)
                    GU[(size_t)(row0 + rr) * 4096 + col] = f2bf(acc[mf][nf][j]);
            }
        }
}

// ================= act: h = silu(g)*u*pw -> Ht128 tiled =================
__global__ __launch_bounds__(256) void act_kernel(
    const short* __restrict__ GU,        // [NPAIR][4096]
    const float* __restrict__ pair_w,
    const int* __restrict__ tile_row0, const int* __restrict__ tile_rows,
    short* __restrict__ Ht)              // [72][32][8][128][8]
{
    const int bid  = blockIdx.x;         // 72*128
    const int tile = bid >> 7;
    const int r    = bid & 127;
    const int rows = tile_rows[tile];
    if (r >= rows) return;
    const int p    = tile_row0[tile] + r;
    const float pw = pair_w[p];
    const int tid  = threadIdx.x;        // col chunk = tid*8, 256 thr cover 2048

    const short* g8p = GU + (size_t)p * 4096 + tid * 8;
    bf16x8 g8 = *(const bf16x8*)g8p;
    bf16x8 u8 = *(const bf16x8*)(g8p + 2048);
    bf16x8 o;
    #pragma unroll
    for (int k = 0; k < 8; ++k) {
        float g = bf2f(g8[k]);
        float u = bf2f(u8[k]);
        float sig = 1.f / (1.f + __expf(-g));
        o[k] = f2bf(g * sig * u * pw);
    }
    *(bf16x8*)(Ht + (size_t)tile * 262144 + (size_t)(tid >> 3) * 8192
               + (tid & 7) * 1024 + r * 8) = o;
}

// ================= GEMM2s: 128x128 tile, BK=64, m97 shape (new) =================
__global__ __launch_bounds__(256, 3) void gemm2s_kernel(
    const short* __restrict__ Ht,       // [72][32][8][128][8]
    const short* __restrict__ Wot,      // [E][32][32][8][128][8]
    const int* __restrict__ pair_token,
    const int* __restrict__ tile_expert, const int* __restrict__ tile_row0,
    const int* __restrict__ tile_rows,
    float* __restrict__ out)            // [T][H]
{
    const int b   = blockIdx.x;          // 2304 = 72*32
    const int l   = (b & 7) * 288 + (b >> 3);
    const int tile  = l >> 5;
    const int n0idx = l & 31;            // over H/128
    const int rows = tile_rows[tile];
    if (rows == 0) return;
    const int e    = tile_expert[tile];
    const int row0 = tile_row0[tile];

    __shared__ short sAB[2048 * 8];      // 32 KB
    __shared__ int   sTok[128];

    const int tid  = threadIdx.x;
    const int lane = tid & 63;
    const int w    = tid >> 6;

    if (tid < 128) sTok[tid] = pair_token[row0 + min(tid, rows - 1)];
    __syncthreads();

    const short* aT = Ht  + (size_t)tile * 262144;
    const short* bT = Wot + ((size_t)e * 32 + n0idx) * 262144;

    const int wr = w >> 1, wc = w & 1;
    const int frow = lane & 15, fsel = lane >> 4;

    f32x4v acc[4][4];
    #pragma unroll
    for (int mf = 0; mf < 4; ++mf)
        #pragma unroll
        for (int nf = 0; nf < 4; ++nf) acc[mf][nf] = (f32x4v)0.f;

    const int KT = I_DIM / 64;           // 32
    for (int kt = 0; kt < KT; ++kt) {
        __syncthreads();
        {
            const size_t ko = (size_t)kt * 8192;
            #pragma unroll
            for (int i = 0; i < 4; ++i) {
                load_lds16(aT + ko + (size_t)tid * 8 + i * 2048,
                           &sAB[(i * 256 + w * 64) * 8]);
                load_lds16(bT + ko + (size_t)tid * 8 + i * 2048,
                           &sAB[((1024 + i * 256 + w * 64)) * 8]);
            }
        }
        __syncthreads();

        #pragma unroll
        for (int h = 0; h < 2; ++h) {
            const int c = h * 4 + fsel;
            bf16x8 af[4];
            #pragma unroll
            for (int mf = 0; mf < 4; ++mf)
                af[mf] = *(const bf16x8*)&sAB[(c * 128 + wr * 64 + mf * 16 + frow) * 8];
            #pragma unroll
            for (int nf = 0; nf < 4; ++nf) {
                bf16x8 bf = *(const bf16x8*)&sAB[(1024 + c * 128 + wc * 64 + nf * 16 + frow) * 8];
                #pragma unroll
                for (int mf = 0; mf < 4; ++mf)
                    acc[mf][nf] = __builtin_amdgcn_mfma_f32_16x16x32_bf16(af[mf], bf, acc[mf][nf], 0, 0, 0);
            }
        }
    }

    const int r4 = fsel * 4;
    #pragma unroll
    for (int mf = 0; mf < 4; ++mf)
        #pragma unroll
        for (int nf = 0; nf < 4; ++nf) {
            const int col = n0idx * 128 + wc * 64 + nf * 16 + frow;
            #pragma unroll
            for (int j = 0; j < 4; ++j) {
                int rr = wr * 64 + mf * 16 + r4 + j;
                if (rr < rows)
                    atomicAdd(out + (size_t)sTok[rr] * H_DIM + col, acc[mf][nf][j]);
            }
        }
}

// ================= FALLBACK PATH (R3) =================
__global__ __launch_bounds__(512, 2) void gemm1_kernel(
    const short* __restrict__ Xbf, const float* __restrict__ Wi0, const float* __restrict__ Wi1,
    const int* __restrict__ pair_token, const float* __restrict__ pair_w,
    const int* __restrict__ t1_expert, const int* __restrict__ t1_row0, const int* __restrict__ t1_rows,
    short* __restrict__ Hbuf)
{
    const int tile = blockIdx.x;
    const int rows = t1_rows[tile];
    if (rows == 0) return;
    const int e    = t1_expert[tile];
    const int row0 = t1_row0[tile];
    const int n0   = blockIdx.y * BN1;

    __shared__ short sA [2][BM1][64];
    __shared__ short sB0[2][BN1][64 + 8];
    __shared__ short sB1[2][BN1][64 + 8];
    __shared__ int   sTok[BM1];
    __shared__ float sPw [BM1];

    const int tid  = threadIdx.x;
    const int lane = tid & 63;
    const int w    = tid >> 6;

    if (tid < BM1) {
        int tr = min(tid, rows - 1);
        sTok[tid] = pair_token[row0 + tr];
        sPw[tid]  = (tid < rows) ? pair_w[row0 + tid] : 0.f;
    }
    __syncthreads();

    const short* aSrc[4];
    #pragma unroll
    for (int i = 0; i < 4; ++i) {
        int r = w * 32 + i * 8 + (lane >> 3);
        int j = lane & 7;
        aSrc[i] = Xbf + (size_t)sTok[r] * H_DIM + ((j ^ (r & 7)) * 8);
    }

    const int brow = tid >> 2;
    const int bq   = tid & 3;
    const size_t wboff = ((size_t)e * I_DIM + (n0 + brow)) * H_DIM + bq * 16;
    const float* b0p = Wi0 + wboff;
    const float* b1p = Wi1 + wboff;

    const int wr   = w >> 1;
    const int wc   = w & 1;
    const int frow = lane & 15;
    const int fsel = lane >> 4;

    f32x4v accg[4][4], accu[4][4];
    #pragma unroll
    for (int mf = 0; mf < 4; ++mf)
        #pragma unroll
        for (int nf = 0; nf < 4; ++nf) { accg[mf][nf] = (f32x4v)0.f; accu[mf][nf] = (f32x4v)0.f; }

    f32x4v rb0[4], rb1[4];

    #pragma unroll
    for (int i = 0; i < 4; ++i)
        load_lds16(aSrc[i], &sA[0][w * 32 + i * 8][0]);
    #pragma unroll
    for (int i = 0; i < 4; ++i) { rb0[i] = *(const f32x4v*)(b0p + i * 4); rb1[i] = *(const f32x4v*)(b1p + i * 4); }
    {
        short* d0 = &sB0[0][brow][bq * 16];
        *(bf16x8*)d0       = pack8(rb0[0], rb0[1]);
        *(bf16x8*)(d0 + 8) = pack8(rb0[2], rb0[3]);
        short* d1 = &sB1[0][brow][bq * 16];
        *(bf16x8*)d1       = pack8(rb1[0], rb1[1]);
        *(bf16x8*)(d1 + 8) = pack8(rb1[2], rb1[3]);
    }
    __syncthreads();

    const int KT = H_DIM / 64;
    for (int kt = 0; kt < KT; ++kt) {
        const int cur = kt & 1, nxt = cur ^ 1;
        if (kt + 1 < KT) {
            #pragma unroll
            for (int i = 0; i < 4; ++i)
                load_lds16(aSrc[i] + (kt + 1) * 64, &sA[nxt][w * 32 + i * 8][0]);
            const float* p0 = b0p + (kt + 1) * 64;
            const float* p1 = b1p + (kt + 1) * 64;
            #pragma unroll
            for (int i = 0; i < 4; ++i) { rb0[i] = *(const f32x4v*)(p0 + i * 4); rb1[i] = *(const f32x4v*)(p1 + i * 4); }
        }
        #pragma unroll
        for (int h = 0; h < 2; ++h) {
            bf16x8 af[4], b0f[4], b1f[4];
            #pragma unroll
            for (int mf = 0; mf < 4; ++mf) {
                int ar = wr * 64 + mf * 16 + frow;
                int c  = (h * 4 + fsel) ^ (ar & 7);
                af[mf] = *(const bf16x8*)((const char*)&sA[cur][0][0] + ar * 128 + c * 16);
            }
            #pragma unroll
            for (int nf = 0; nf < 4; ++nf) {
                int br = wc * 64 + nf * 16 + frow;
                b0f[nf] = *(const bf16x8*)&sB0[cur][br][h * 32 + fsel * 8];
                b1f[nf] = *(const bf16x8*)&sB1[cur][br][h * 32 + fsel * 8];
            }
            #pragma unroll
            for (int nf = 0; nf < 4; ++nf)
                #pragma unroll
                for (int mf = 0; mf < 4; ++mf) {
                    accg[mf][nf] = __builtin_amdgcn_mfma_f32_16x16x32_bf16(af[mf], b0f[nf], accg[mf][nf], 0, 0, 0);
                    accu[mf][nf] = __builtin_amdgcn_mfma_f32_16x16x32_bf16(af[mf], b1f[nf], accu[mf][nf], 0, 0, 0);
                }
        }
        if (kt + 1 < KT) {
            short* d0 = &sB0[nxt][brow][bq * 16];
            *(bf16x8*)d0       = pack8(rb0[0], rb0[1]);
            *(bf16x8*)(d0 + 8) = pack8(rb0[2], rb0[3]);
            short* d1 = &sB1[nxt][brow][bq * 16];
            *(bf16x8*)d1       = pack8(rb1[0], rb1[1]);
            *(bf16x8*)(d1 + 8) = pack8(rb1[2], rb1[3]);
        }
        __syncthreads();
    }

    const int r4 = fsel * 4;
    #pragma unroll
    for (int mf = 0; mf < 4; ++mf)
        #pragma unroll
        for (int nf = 0; nf < 4; ++nf)
            #pragma unroll
            for (int j = 0; j < 4; ++j) {
                int rr = wr * 64 + mf * 16 + r4 + j;
                if (rr < rows) {
                    float g = accg[mf][nf][j];
                    float u = accu[mf][nf][j];
                    float sig = 1.f / (1.f + __expf(-g));
                    float v = g * sig * u * sPw[rr];
                    int col = n0 + wc * 64 + nf * 16 + frow;
                    Hbuf[(size_t)(row0 + rr) * I_DIM + col] = f2bf(v);
                }
            }
}

__global__ __launch_bounds__(256, 2) void gemm2_kernel(
    const short* __restrict__ Hbuf, const float* __restrict__ Wo,
    const int* __restrict__ pair_token,
    const int* __restrict__ tile_expert, const int* __restrict__ tile_row0,
    const int* __restrict__ tile_rows,
    float* __restrict__ out)
{
    const int tile = blockIdx.x;
    const int rows = tile_rows[tile];
    if (rows == 0) return;
    const int e    = tile_expert[tile];
    const int row0 = tile_row0[tile];
    const int n0   = blockIdx.y * 256;

    __shared__ short sA[BM][BK + 8];
    __shared__ short sB[256][BK + 8];
    __shared__ int   sTok[BM];

    const int tid = threadIdx.x;
    if (tid < BM) sTok[tid] = pair_token[row0 + min(tid, rows - 1)];
    __syncthreads();

    const int srow  = tid >> 1;
    const int shalf = tid & 1;

    const short* aptr = Hbuf + (size_t)(row0 + min(srow, rows - 1)) * I_DIM + shalf * 16;
    const float* bptrA = Wo + ((size_t)e * H_DIM + (n0 + srow))       * I_DIM + shalf * 16;
    const float* bptrB = Wo + ((size_t)e * H_DIM + (n0 + srow + 128)) * I_DIM + shalf * 16;

    bf16x8 ra[2];
    f32x4v rbA[4], rbB[4];
    f32x4v acc[4][8];
    #pragma unroll
    for (int mf = 0; mf < 4; ++mf)
        #pragma unroll
        for (int nf = 0; nf < 8; ++nf) acc[mf][nf] = (f32x4v)0.f;

    const int lane = tid & 63;
    const int wid  = tid >> 6;
    const int wr   = wid >> 1;
    const int wc   = wid & 1;
    const int frow = lane & 15;
    const int fk   = (lane >> 4) * 8;

    ra[0] = *(const bf16x8*)(aptr);
    ra[1] = *(const bf16x8*)(aptr + 8);
    #pragma unroll
    for (int i = 0; i < 4; ++i) { rbA[i] = *(const f32x4v*)(bptrA + i * 4); rbB[i] = *(const f32x4v*)(bptrB + i * 4); }

    const int KT = I_DIM / BK;
    for (int kt = 0; kt < KT; ++kt) {
        __syncthreads();
        *(bf16x8*)&sA[srow][shalf * 16]           = ra[0];
        *(bf16x8*)&sA[srow][shalf * 16 + 8]       = ra[1];
        *(bf16x8*)&sB[srow][shalf * 16]           = pack8(rbA[0], rbA[1]);
        *(bf16x8*)&sB[srow][shalf * 16 + 8]       = pack8(rbA[2], rbA[3]);
        *(bf16x8*)&sB[srow + 128][shalf * 16]     = pack8(rbB[0], rbB[1]);
        *(bf16x8*)&sB[srow + 128][shalf * 16 + 8] = pack8(rbB[2], rbB[3]);
        __syncthreads();

        if (kt + 1 < KT) {
            const int k = (kt + 1) * BK;
            ra[0] = *(const bf16x8*)(aptr + k);
            ra[1] = *(const bf16x8*)(aptr + k + 8);
            #pragma unroll
            for (int i = 0; i < 4; ++i) { rbA[i] = *(const f32x4v*)(bptrA + k + i * 4); rbB[i] = *(const f32x4v*)(bptrB + k + i * 4); }
        }

        bf16x8 af[4];
        #pragma unroll
        for (int mf = 0; mf < 4; ++mf)
            af[mf] = *(const bf16x8*)&sA[wr * 64 + mf * 16 + frow][fk];
        #pragma unroll
        for (int nf = 0; nf < 8; ++nf) {
            bf16x8 bfv = *(const bf16x8*)&sB[wc * 128 + nf * 16 + frow][fk];
            #pragma unroll
            for (int mf = 0; mf < 4; ++mf)
                acc[mf][nf] = __builtin_amdgcn_mfma_f32_16x16x32_bf16(af[mf], bfv, acc[mf][nf], 0, 0, 0);
        }
    }

    const int r4 = (lane >> 4) * 4;
    #pragma unroll
    for (int mf = 0; mf < 4; ++mf)
        #pragma unroll
        for (int nf = 0; nf < 8; ++nf)
            #pragma unroll
            for (int j = 0; j < 4; ++j) {
                int rr = wr * 64 + mf * 16 + r4 + j;
                if (rr < rows) {
                    int col = n0 + wc * 128 + nf * 16 + (lane & 15);
                    atomicAdd(out + (size_t)sTok[rr] * H_DIM + col, acc[mf][nf][j]);
                }
            }
}

// ---------------- launch ----------------
extern "C" void kernel_launch(void* const* d_in, const int* in_sizes, int n_in,
                              void* d_out, int out_size, void* d_ws, size_t ws_size,
                              hipStream_t stream)
{
    (void)in_sizes; (void)n_in;
    const float* X     = (const float*)d_in[0];
    const float* topw  = (const float*)d_in[1];
    const int*   topid = (const int*)d_in[2];
    const float* Wi0   = (const float*)d_in[3];
    const float* Wi1   = (const float*)d_in[4];
    const float* Wo    = (const float*)d_in[5];
    float* out = (float*)d_out;

    char* ws = (char*)d_ws;
    int*   pair_token  = (int*)ws;
    float* pair_w      = (float*)(ws + NPAIR * 4);
    int*   tile_expert = (int*)(ws + NPAIR * 8);
    int*   tile_row0   = tile_expert + MAXT;
    int*   tile_rows   = tile_row0 + MAXT;
    int*   t1_expert   = tile_rows + MAXT;
    int*   t1_row0     = t1_expert + MAXT1;
    int*   t1_rows     = t1_row0 + MAXT1;

    route_kernel<<<1, 256, 0, stream>>>(topid, topw, pair_token, pair_w,
                                        tile_expert, tile_row0, tile_rows,
                                        t1_expert, t1_row0, t1_rows);

    if (ws_size >= NEED_NEW) {
        short* Ht  = (short*)(ws + HT_OFF);
        short* At  = (short*)(ws + AT_OFF);
        short* Ws  = (short*)(ws + WS_OFF);
        short* Wot = (short*)(ws + W0_OFF);   // overlays At/Ws (dead after gemm1s)
        short* GU  = (short*)d_out;           // 67MB scratch, reclaimed by memset

        aprep128_kernel<<<2304, 256, 0, stream>>>(X, pair_token, tile_row0, tile_rows, At);
        wsprep_kernel<<<8192, 256, 0, stream>>>(Wi0, Wi1, Ws);

        gemm1s_kernel<<<2304, 256, 0, stream>>>(
            At, Ws, tile_expert, tile_row0, tile_rows, GU);

        act_kernel<<<MAXT * 128, 256, 0, stream>>>(GU, pair_w, tile_row0, tile_rows, Ht);

        hipMemsetAsync(d_out, 0, (size_t)out_size * sizeof(float), stream);

        woprep2_kernel<<<4096, 256, 0, stream>>>(Wo, Wot);

        gemm2s_kernel<<<2304, 256, 0, stream>>>(
            Ht, Wot, pair_token, tile_expert, tile_row0, tile_rows, out);
    } else {
        short* Hbuf = (short*)(ws + (1 << 20));
        short* Xbf  = (short*)d_out;

        cvt_kernel<<<T_TOK * H_DIM / (256 * 8), 256, 0, stream>>>(X, Xbf);

        gemm1_kernel<<<dim3(MAXT1, I_DIM / BN1), 512, 0, stream>>>(
            Xbf, Wi0, Wi1, pair_token, pair_w, t1_expert, t1_row0, t1_rows, Hbuf);

        hipMemsetAsync(d_out, 0, (size_t)out_size * sizeof(float), stream);

        gemm2_kernel<<<dim3(MAXT, H_DIM / 256), 256, 0, stream>>>(
            Hbuf, Wo, pair_token, tile_expert, tile_row0, tile_rows, out);
    }
}

// Round 12
// 825.743 us; speedup vs baseline: 1.4508x; 1.0716x over previous
//
#include <hip/hip_runtime.h>
#include <hip/hip_bf16.h>

#define T_TOK 4096
#define H_DIM 4096
#define I_DIM 2048
#define N_EXP 8
#define TOPK  2
#define NPAIR (T_TOK*TOPK)          // 8192
#define BM    128
#define BK    32
#define MAXT  (NPAIR/BM + N_EXP)    // 72
#define BM1   256
#define BN1   128
#define MAXT1 (NPAIR/BM1 + N_EXP)   // 40

// ---- workspace offsets (bytes) ----
#define HT_OFF   ((size_t)1 << 20)                  // Ht128: 37.7MB
#define W0_OFF   ((size_t)44 << 20)                 // Wot128: 134MB (written AFTER gemm1f)
#define AT_OFF   ((size_t)44 << 20)                 // At128: 72MB (dead after gemm1f)
#define WS_OFF   ((size_t)120 << 20)                // Ws paired bf16: 268MB (dead after gemm1f)
#define NEED_NEW (WS_OFF + 268435456ull)            // ~376 MiB

typedef __attribute__((ext_vector_type(8))) short  bf16x8;
typedef __attribute__((ext_vector_type(4))) float  f32x4v;

__device__ __forceinline__ short f2bf(float f) {
    __hip_bfloat16 h = __float2bfloat16(f);
    return __builtin_bit_cast(short, h);
}
__device__ __forceinline__ float bf2f(short s) {
    unsigned int u = ((unsigned int)(unsigned short)s) << 16;
    return __builtin_bit_cast(float, u);
}

__device__ __forceinline__ bf16x8 pack8(f32x4v a, f32x4v b) {
    bf16x8 r;
    r[0]=f2bf(a[0]); r[1]=f2bf(a[1]); r[2]=f2bf(a[2]); r[3]=f2bf(a[3]);
    r[4]=f2bf(b[0]); r[5]=f2bf(b[1]); r[6]=f2bf(b[2]); r[7]=f2bf(b[3]);
    return r;
}

__device__ __forceinline__ void load_lds16(const short* g, short* l) {
    __builtin_amdgcn_global_load_lds(
        (const __attribute__((address_space(1))) void*)g,
        (__attribute__((address_space(3))) void*)l, 16, 0, 0);
}

// ---------------- fp32 -> bf16 plain (fallback X path) ----------------
__global__ void cvt_kernel(const float* __restrict__ X, short* __restrict__ Xbf) {
    const size_t i = ((size_t)blockIdx.x * 256 + threadIdx.x) * 8;
    f32x4v a = *(const f32x4v*)(X + i);
    f32x4v b = *(const f32x4v*)(X + i + 4);
    *(bf16x8*)(Xbf + i) = pack8(a, b);
}

// ---------------- routing ----------------
__global__ void route_kernel(const int* __restrict__ ids, const float* __restrict__ wts,
                             int* __restrict__ pair_token, float* __restrict__ pair_w,
                             int* __restrict__ tile_expert, int* __restrict__ tile_row0,
                             int* __restrict__ tile_rows,
                             int* __restrict__ t1_expert, int* __restrict__ t1_row0,
                             int* __restrict__ t1_rows)
{
    __shared__ int scn[256][N_EXP];
    const int tid = threadIdx.x;
    const int PPT = NPAIR / 256;
    const int base = tid * PPT;

    int c[N_EXP], orig[N_EXP];
    #pragma unroll
    for (int e = 0; e < N_EXP; ++e) c[e] = 0;
    for (int p = 0; p < PPT; ++p) c[ids[base + p]]++;
    #pragma unroll
    for (int e = 0; e < N_EXP; ++e) { orig[e] = c[e]; scn[tid][e] = c[e]; }
    __syncthreads();

    for (int off = 1; off < 256; off <<= 1) {
        int add[N_EXP];
        #pragma unroll
        for (int e = 0; e < N_EXP; ++e) add[e] = (tid >= off) ? scn[tid - off][e] : 0;
        __syncthreads();
        #pragma unroll
        for (int e = 0; e < N_EXP; ++e) { c[e] += add[e]; scn[tid][e] = c[e]; }
        __syncthreads();
    }

    int segs[N_EXP + 1];
    {
        int run = 0;
        #pragma unroll
        for (int e = 0; e < N_EXP; ++e) { segs[e] = run; run += scn[255][e]; }
        segs[N_EXP] = run;
    }
    int pos[N_EXP];
    #pragma unroll
    for (int e = 0; e < N_EXP; ++e) pos[e] = segs[e] + c[e] - orig[e];

    for (int p = 0; p < PPT; ++p) {
        int pp = base + p;
        int e = ids[pp];
        int q = pos[e]++;
        pair_token[q] = pp / TOPK;
        pair_w[q]     = wts[pp];
    }

    if (tid == 0) {
        int t = 0;
        for (int e = 0; e < N_EXP; ++e) {
            int s = segs[e], en = segs[e + 1];
            for (int r = s; r < en; r += BM) {
                tile_expert[t] = e; tile_row0[t] = r; tile_rows[t] = min(BM, en - r); ++t;
            }
        }
        for (; t < MAXT; ++t) { tile_expert[t] = 0; tile_row0[t] = 0; tile_rows[t] = 0; }

        t = 0;
        for (int e = 0; e < N_EXP; ++e) {
            int s = segs[e], en = segs[e + 1];
            for (int r = s; r < en; r += BM1) {
                t1_expert[t] = e; t1_row0[t] = r; t1_rows[t] = min(BM1, en - r); ++t;
            }
        }
        for (; t < MAXT1; ++t) { t1_expert[t] = 0; t1_row0[t] = 0; t1_rows[t] = 0; }
    }
}

// ================= coalesced LDS-transpose preps =================
#define PRP 132

// Paired Wi -> Ws [e][slice 32][kt 64][q 8][panel-row 128][x 8]
//   panel rows 0-63 = Wi0 rows slice*64+0..63 (gate), rows 64-127 = Wi1 rows slice*64.. (up)
__global__ __launch_bounds__(256) void wsprep_kernel(const float* __restrict__ Wi0,
                                                     const float* __restrict__ Wi1,
                                                     short* __restrict__ Ws) {
    const int bid = blockIdx.x;          // 8 * 32 * 32 = 8192
    const int e   = bid >> 10;
    const int nt  = (bid >> 5) & 31;     // slice
    const int ktg = bid & 31;
    __shared__ short lds[128][PRP];
    const int tid = threadIdx.x;
    const float* srcG = Wi0 + ((size_t)e * 2048 + nt * 64) * 4096 + ktg * 128;
    const float* srcU = Wi1 + ((size_t)e * 2048 + nt * 64) * 4096 + ktg * 128;
    #pragma unroll
    for (int it = 0; it < 8; ++it) {
        int r  = it * 16 + (tid >> 4);   // panel row 0..127
        int hc = (tid & 15) * 8;
        const float* s = (r < 64) ? (srcG + (size_t)r * 4096 + hc)
                                  : (srcU + (size_t)(r - 64) * 4096 + hc);
        f32x4v a = *(const f32x4v*)s;
        f32x4v b = *(const f32x4v*)(s + 4);
        *(bf16x8*)&lds[r][hc] = pack8(a, b);
    }
    __syncthreads();
    short* dst = Ws + ((size_t)(e * 32 + nt)) * 524288 + (size_t)ktg * 2 * 8192;
    #pragma unroll
    for (int it = 0; it < 8; ++it) {
        int idx = it * 256 + tid;
        int c8  = idx >> 7;
        int r   = idx & 127;
        bf16x8 v = *(const bf16x8*)&lds[r][c8 * 8];
        *(bf16x8*)(dst + (size_t)(c8 >> 3) * 8192 + (c8 & 7) * 1024 + r * 8) = v;
    }
}

// X gather -> At128 [tile 72][kt 64][q 8][r 128][x 8]
__global__ __launch_bounds__(256) void aprep128_kernel(const float* __restrict__ X,
                             const int* __restrict__ pair_token,
                             const int* __restrict__ tile_row0, const int* __restrict__ tile_rows,
                             short* __restrict__ At) {
    const int bid  = blockIdx.x;         // 72 * 32 = 2304
    const int tile = bid >> 5;
    const int ktg  = bid & 31;
    const int rows = tile_rows[tile];
    if (rows == 0) return;
    const int row0 = tile_row0[tile];
    __shared__ short lds[128][PRP];
    const int tid = threadIdx.x;
    #pragma unroll
    for (int it = 0; it < 8; ++it) {
        int r  = it * 16 + (tid >> 4);
        int hc = (tid & 15) * 8;
        int tok = pair_token[row0 + min(r, rows - 1)];
        const float* s = X + (size_t)tok * 4096 + ktg * 128 + hc;
        f32x4v a = *(const f32x4v*)s;
        f32x4v b = *(const f32x4v*)(s + 4);
        *(bf16x8*)&lds[r][hc] = pack8(a, b);
    }
    __syncthreads();
    short* dst = At + (size_t)tile * 524288 + (size_t)ktg * 2 * 8192;
    #pragma unroll
    for (int it = 0; it < 8; ++it) {
        int idx = it * 256 + tid;
        int c8  = idx >> 7;
        int r   = idx & 127;
        bf16x8 v = *(const bf16x8*)&lds[r][c8 * 8];
        *(bf16x8*)(dst + (size_t)(c8 >> 3) * 8192 + (c8 & 7) * 1024 + r * 8) = v;
    }
}

// Wo (E,H,I) fp32 -> Wot128 [e][hb 32][kt 32][q 8][r 128][x 8]
__global__ __launch_bounds__(256) void woprep2_kernel(const float* __restrict__ W, short* __restrict__ Wt) {
    const int bid = blockIdx.x;          // 4096
    const int e   = bid >> 9;
    const int hb  = (bid >> 4) & 31;
    const int ktg = bid & 15;
    __shared__ short lds[128][PRP];
    const int tid = threadIdx.x;
    const float* src0 = W + ((size_t)(e * 4096 + hb * 128)) * 2048 + ktg * 128;
    #pragma unroll
    for (int it = 0; it < 8; ++it) {
        int r  = it * 16 + (tid >> 4);
        int hc = (tid & 15) * 8;
        const float* s = src0 + (size_t)r * 2048 + hc;
        f32x4v a = *(const f32x4v*)s;
        f32x4v b = *(const f32x4v*)(s + 4);
        *(bf16x8*)&lds[r][hc] = pack8(a, b);
    }
    __syncthreads();
    short* dst = Wt + ((size_t)(e * 32 + hb)) * 262144 + (size_t)ktg * 2 * 8192;
    #pragma unroll
    for (int it = 0; it < 8; ++it) {
        int idx = it * 256 + tid;
        int c8  = idx >> 7;
        int r   = idx & 127;
        bf16x8 v = *(const bf16x8*)&lds[r][c8 * 8];
        *(bf16x8*)(dst + (size_t)(c8 >> 3) * 8192 + (c8 & 7) * 1024 + r * 8) = v;
    }
}

// ================= GEMM1f: fused gate/up + silu, 128x128 tile, BK=64 =================
// Per block: 128 rows x (64 gate + 64 up cols of slice n0idx). Wave w = rows w*32..w*32+31,
// all 128 B-panel cols. Same lane holds gate col k (nf) and up col k (nf+4) -> in-reg silu.
__global__ __launch_bounds__(256, 3) void gemm1f_kernel(
    const short* __restrict__ At,       // [72][64][8][128][8]
    const short* __restrict__ Ws,       // [E][32][64][8][128gate|up][8]
    const float* __restrict__ pair_w,
    const int* __restrict__ tile_expert, const int* __restrict__ tile_row0,
    const int* __restrict__ tile_rows,
    short* __restrict__ Ht)             // [72][32][8][128][8]
{
    const int b   = blockIdx.x;          // 2304 = 72*32
    const int l   = (b & 7) * 288 + (b >> 3);
    const int tile  = l >> 5;
    const int n0idx = l & 31;            // I-slice of 64
    const int rows = tile_rows[tile];
    if (rows == 0) return;
    const int e    = tile_expert[tile];
    const int row0 = tile_row0[tile];

    __shared__ short sAB[2048 * 8];      // 32 KB
    __shared__ float sPw[128];

    const int tid  = threadIdx.x;
    const int lane = tid & 63;
    const int w    = tid >> 6;

    if (tid < 128) sPw[tid] = (tid < rows) ? pair_w[row0 + tid] : 0.f;
    __syncthreads();

    const short* aT = At + (size_t)tile * 524288;
    const short* bT = Ws + ((size_t)e * 32 + n0idx) * 524288;

    const int frow = lane & 15, fsel = lane >> 4;

    f32x4v acc[2][8];
    #pragma unroll
    for (int mf = 0; mf < 2; ++mf)
        #pragma unroll
        for (int nf = 0; nf < 8; ++nf) acc[mf][nf] = (f32x4v)0.f;

    const int KT = H_DIM / 64;           // 64
    for (int kt = 0; kt < KT; ++kt) {
        __syncthreads();
        {
            const size_t ko = (size_t)kt * 8192;
            #pragma unroll
            for (int i = 0; i < 4; ++i) {
                load_lds16(aT + ko + (size_t)tid * 8 + i * 2048,
                           &sAB[(i * 256 + w * 64) * 8]);
                load_lds16(bT + ko + (size_t)tid * 8 + i * 2048,
                           &sAB[((1024 + i * 256 + w * 64)) * 8]);
            }
        }
        __syncthreads();

        #pragma unroll
        for (int h = 0; h < 2; ++h) {
            const int c = h * 4 + fsel;
            bf16x8 af[2];
            #pragma unroll
            for (int mf = 0; mf < 2; ++mf)
                af[mf] = *(const bf16x8*)&sAB[(c * 128 + w * 32 + mf * 16 + frow) * 8];
            #pragma unroll
            for (int nf = 0; nf < 8; ++nf) {
                bf16x8 bf = *(const bf16x8*)&sAB[(1024 + c * 128 + nf * 16 + frow) * 8];
                #pragma unroll
                for (int mf = 0; mf < 2; ++mf)
                    acc[mf][nf] = __builtin_amdgcn_mfma_f32_16x16x32_bf16(af[mf], bf, acc[mf][nf], 0, 0, 0);
            }
        }
    }

    // fused epilogue: v = silu(g)*u*pw -> Ht (scalar bf16 stores)
    #pragma unroll
    for (int mf = 0; mf < 2; ++mf)
        #pragma unroll
        for (int nfg = 0; nfg < 4; ++nfg) {
            const int c_g = n0idx * 64 + nfg * 16 + frow;   // I-col
            const size_t cb = (size_t)tile * 262144 + (size_t)(c_g >> 6) * 8192
                            + ((c_g >> 3) & 7) * 1024 + (c_g & 7);
            #pragma unroll
            for (int j = 0; j < 4; ++j) {
                int row = w * 32 + mf * 16 + fsel * 4 + j;
                if (row < rows) {
                    float g = acc[mf][nfg][j];
                    float u = acc[mf][nfg + 4][j];
                    float sig = 1.f / (1.f + __expf(-g));
                    Ht[cb + (size_t)row * 8] = f2bf(g * sig * u * sPw[row]);
                }
            }
        }
}

// ================= GEMM2s: 128x128 tile, BK=64, m97 shape (proven R11) =================
__global__ __launch_bounds__(256, 3) void gemm2s_kernel(
    const short* __restrict__ Ht,       // [72][32][8][128][8]
    const short* __restrict__ Wot,      // [E][32][32][8][128][8]
    const int* __restrict__ pair_token,
    const int* __restrict__ tile_expert, const int* __restrict__ tile_row0,
    const int* __restrict__ tile_rows,
    float* __restrict__ out)            // [T][H]
{
    const int b   = blockIdx.x;          // 2304 = 72*32
    const int l   = (b & 7) * 288 + (b >> 3);
    const int tile  = l >> 5;
    const int n0idx = l & 31;            // over H/128
    const int rows = tile_rows[tile];
    if (rows == 0) return;
    const int e    = tile_expert[tile];
    const int row0 = tile_row0[tile];

    __shared__ short sAB[2048 * 8];      // 32 KB
    __shared__ int   sTok[128];

    const int tid  = threadIdx.x;
    const int lane = tid & 63;
    const int w    = tid >> 6;

    if (tid < 128) sTok[tid] = pair_token[row0 + min(tid, rows - 1)];
    __syncthreads();

    const short* aT = Ht  + (size_t)tile * 262144;
    const short* bT = Wot + ((size_t)e * 32 + n0idx) * 262144;

    const int wr = w >> 1, wc = w & 1;
    const int frow = lane & 15, fsel = lane >> 4;

    f32x4v acc[4][4];
    #pragma unroll
    for (int mf = 0; mf < 4; ++mf)
        #pragma unroll
        for (int nf = 0; nf < 4; ++nf) acc[mf][nf] = (f32x4v)0.f;

    const int KT = I_DIM / 64;           // 32
    for (int kt = 0; kt < KT; ++kt) {
        __syncthreads();
        {
            const size_t ko = (size_t)kt * 8192;
            #pragma unroll
            for (int i = 0; i < 4; ++i) {
                load_lds16(aT + ko + (size_t)tid * 8 + i * 2048,
                           &sAB[(i * 256 + w * 64) * 8]);
                load_lds16(bT + ko + (size_t)tid * 8 + i * 2048,
                           &sAB[((1024 + i * 256 + w * 64)) * 8]);
            }
        }
        __syncthreads();

        #pragma unroll
        for (int h = 0; h < 2; ++h) {
            const int c = h * 4 + fsel;
            bf16x8 af[4];
            #pragma unroll
            for (int mf = 0; mf < 4; ++mf)
                af[mf] = *(const bf16x8*)&sAB[(c * 128 + wr * 64 + mf * 16 + frow) * 8];
            #pragma unroll
            for (int nf = 0; nf < 4; ++nf) {
                bf16x8 bf = *(const bf16x8*)&sAB[(1024 + c * 128 + wc * 64 + nf * 16 + frow) * 8];
                #pragma unroll
                for (int mf = 0; mf < 4; ++mf)
                    acc[mf][nf] = __builtin_amdgcn_mfma_f32_16x16x32_bf16(af[mf], bf, acc[mf][nf], 0, 0, 0);
            }
        }
    }

    const int r4 = fsel * 4;
    #pragma unroll
    for (int mf = 0; mf < 4; ++mf)
        #pragma unroll
        for (int nf = 0; nf < 4; ++nf) {
            const int col = n0idx * 128 + wc * 64 + nf * 16 + frow;
            #pragma unroll
            for (int j = 0; j < 4; ++j) {
                int rr = wr * 64 + mf * 16 + r4 + j;
                if (rr < rows)
                    atomicAdd(out + (size_t)sTok[rr] * H_DIM + col, acc[mf][nf][j]);
            }
        }
}

// ================= FALLBACK PATH (R3) =================
__global__ __launch_bounds__(512, 2) void gemm1_kernel(
    const short* __restrict__ Xbf, const float* __restrict__ Wi0, const float* __restrict__ Wi1,
    const int* __restrict__ pair_token, const float* __restrict__ pair_w,
    const int* __restrict__ t1_expert, const int* __restrict__ t1_row0, const int* __restrict__ t1_rows,
    short* __restrict__ Hbuf)
{
    const int tile = blockIdx.x;
    const int rows = t1_rows[tile];
    if (rows == 0) return;
    const int e    = t1_expert[tile];
    const int row0 = t1_row0[tile];
    const int n0   = blockIdx.y * BN1;

    __shared__ short sA [2][BM1][64];
    __shared__ short sB0[2][BN1][64 + 8];
    __shared__ short sB1[2][BN1][64 + 8];
    __shared__ int   sTok[BM1];
    __shared__ float sPw [BM1];

    const int tid  = threadIdx.x;
    const int lane = tid & 63;
    const int w    = tid >> 6;

    if (tid < BM1) {
        int tr = min(tid, rows - 1);
        sTok[tid] = pair_token[row0 + tr];
        sPw[tid]  = (tid < rows) ? pair_w[row0 + tid] : 0.f;
    }
    __syncthreads();

    const short* aSrc[4];
    #pragma unroll
    for (int i = 0; i < 4; ++i) {
        int r = w * 32 + i * 8 + (lane >> 3);
        int j = lane & 7;
        aSrc[i] = Xbf + (size_t)sTok[r] * H_DIM + ((j ^ (r & 7)) * 8);
    }

    const int brow = tid >> 2;
    const int bq   = tid & 3;
    const size_t wboff = ((size_t)e * I_DIM + (n0 + brow)) * H_DIM + bq * 16;
    const float* b0p = Wi0 + wboff;
    const float* b1p = Wi1 + wboff;

    const int wr   = w >> 1;
    const int wc   = w & 1;
    const int frow = lane & 15;
    const int fsel = lane >> 4;

    f32x4v accg[4][4], accu[4][4];
    #pragma unroll
    for (int mf = 0; mf < 4; ++mf)
        #pragma unroll
        for (int nf = 0; nf < 4; ++nf) { accg[mf][nf] = (f32x4v)0.f; accu[mf][nf] = (f32x4v)0.f; }

    f32x4v rb0[4], rb1[4];

    #pragma unroll
    for (int i = 0; i < 4; ++i)
        load_lds16(aSrc[i], &sA[0][w * 32 + i * 8][0]);
    #pragma unroll
    for (int i = 0; i < 4; ++i) { rb0[i] = *(const f32x4v*)(b0p + i * 4); rb1[i] = *(const f32x4v*)(b1p + i * 4); }
    {
        short* d0 = &sB0[0][brow][bq * 16];
        *(bf16x8*)d0       = pack8(rb0[0], rb0[1]);
        *(bf16x8*)(d0 + 8) = pack8(rb0[2], rb0[3]);
        short* d1 = &sB1[0][brow][bq * 16];
        *(bf16x8*)d1       = pack8(rb1[0], rb1[1]);
        *(bf16x8*)(d1 + 8) = pack8(rb1[2], rb1[3]);
    }
    __syncthreads();

    const int KT = H_DIM / 64;
    for (int kt = 0; kt < KT; ++kt) {
        const int cur = kt & 1, nxt = cur ^ 1;
        if (kt + 1 < KT) {
            #pragma unroll
            for (int i = 0; i < 4; ++i)
                load_lds16(aSrc[i] + (kt + 1) * 64, &sA[nxt][w * 32 + i * 8][0]);
            const float* p0 = b0p + (kt + 1) * 64;
            const float* p1 = b1p + (kt + 1) * 64;
            #pragma unroll
            for (int i = 0; i < 4; ++i) { rb0[i] = *(const f32x4v*)(p0 + i * 4); rb1[i] = *(const f32x4v*)(p1 + i * 4); }
        }
        #pragma unroll
        for (int h = 0; h < 2; ++h) {
            bf16x8 af[4], b0f[4], b1f[4];
            #pragma unroll
            for (int mf = 0; mf < 4; ++mf) {
                int ar = wr * 64 + mf * 16 + frow;
                int c  = (h * 4 + fsel) ^ (ar & 7);
                af[mf] = *(const bf16x8*)((const char*)&sA[cur][0][0] + ar * 128 + c * 16);
            }
            #pragma unroll
            for (int nf = 0; nf < 4; ++nf) {
                int br = wc * 64 + nf * 16 + frow;
                b0f[nf] = *(const bf16x8*)&sB0[cur][br][h * 32 + fsel * 8];
                b1f[nf] = *(const bf16x8*)&sB1[cur][br][h * 32 + fsel * 8];
            }
            #pragma unroll
            for (int nf = 0; nf < 4; ++nf)
                #pragma unroll
                for (int mf = 0; mf < 4; ++mf) {
                    accg[mf][nf] = __builtin_amdgcn_mfma_f32_16x16x32_bf16(af[mf], b0f[nf], accg[mf][nf], 0, 0, 0);
                    accu[mf][nf] = __builtin_amdgcn_mfma_f32_16x16x32_bf16(af[mf], b1f[nf], accu[mf][nf], 0, 0, 0);
                }
        }
        if (kt + 1 < KT) {
            short* d0 = &sB0[nxt][brow][bq * 16];
            *(bf16x8*)d0       = pack8(rb0[0], rb0[1]);
            *(bf16x8*)(d0 + 8) = pack8(rb0[2], rb0[3]);
            short* d1 = &sB1[nxt][brow][bq * 16];
            *(bf16x8*)d1       = pack8(rb1[0], rb1[1]);
            *(bf16x8*)(d1 + 8) = pack8(rb1[2], rb1[3]);
        }
        __syncthreads();
    }

    const int r4 = fsel * 4;
    #pragma unroll
    for (int mf = 0; mf < 4; ++mf)
        #pragma unroll
        for (int nf = 0; nf < 4; ++nf)
            #pragma unroll
            for (int j = 0; j < 4; ++j) {
                int rr = wr * 64 + mf * 16 + r4 + j;
                if (rr < rows) {
                    float g = accg[mf][nf][j];
                    float u = accu[mf][nf][j];
                    float sig = 1.f / (1.f + __expf(-g));
                    float v = g * sig * u * sPw[rr];
                    int col = n0 + wc * 64 + nf * 16 + frow;
                    Hbuf[(size_t)(row0 + rr) * I_DIM + col] = f2bf(v);
                }
            }
}

__global__ __launch_bounds__(256, 2) void gemm2_kernel(
    const short* __restrict__ Hbuf, const float* __restrict__ Wo,
    const int* __restrict__ pair_token,
    const int* __restrict__ tile_expert, const int* __restrict__ tile_row0,
    const int* __restrict__ tile_rows,
    float* __restrict__ out)
{
    const int tile = blockIdx.x;
    const int rows = tile_rows[tile];
    if (rows == 0) return;
    const int e    = tile_expert[tile];
    const int row0 = tile_row0[tile];
    const int n0   = blockIdx.y * 256;

    __shared__ short sA[BM][BK + 8];
    __shared__ short sB[256][BK + 8];
    __shared__ int   sTok[BM];

    const int tid = threadIdx.x;
    if (tid < BM) sTok[tid] = pair_token[row0 + min(tid, rows - 1)];
    __syncthreads();

    const int srow  = tid >> 1;
    const int shalf = tid & 1;

    const short* aptr = Hbuf + (size_t)(row0 + min(srow, rows - 1)) * I_DIM + shalf * 16;
    const float* bptrA = Wo + ((size_t)e * H_DIM + (n0 + srow))       * I_DIM + shalf * 16;
    const float* bptrB = Wo + ((size_t)e * H_DIM + (n0 + srow + 128)) * I_DIM + shalf * 16;

    bf16x8 ra[2];
    f32x4v rbA[4], rbB[4];
    f32x4v acc[4][8];
    #pragma unroll
    for (int mf = 0; mf < 4; ++mf)
        #pragma unroll
        for (int nf = 0; nf < 8; ++nf) acc[mf][nf] = (f32x4v)0.f;

    const int lane = tid & 63;
    const int wid  = tid >> 6;
    const int wr   = wid >> 1;
    const int wc   = wid & 1;
    const int frow = lane & 15;
    const int fk   = (lane >> 4) * 8;

    ra[0] = *(const bf16x8*)(aptr);
    ra[1] = *(const bf16x8*)(aptr + 8);
    #pragma unroll
    for (int i = 0; i < 4; ++i) { rbA[i] = *(const f32x4v*)(bptrA + i * 4); rbB[i] = *(const f32x4v*)(bptrB + i * 4); }

    const int KT = I_DIM / BK;
    for (int kt = 0; kt < KT; ++kt) {
        __syncthreads();
        *(bf16x8*)&sA[srow][shalf * 16]           = ra[0];
        *(bf16x8*)&sA[srow][shalf * 16 + 8]       = ra[1];
        *(bf16x8*)&sB[srow][shalf * 16]           = pack8(rbA[0], rbA[1]);
        *(bf16x8*)&sB[srow][shalf * 16 + 8]       = pack8(rbA[2], rbA[3]);
        *(bf16x8*)&sB[srow + 128][shalf * 16]     = pack8(rbB[0], rbB[1]);
        *(bf16x8*)&sB[srow + 128][shalf * 16 + 8] = pack8(rbB[2], rbB[3]);
        __syncthreads();

        if (kt + 1 < KT) {
            const int k = (kt + 1) * BK;
            ra[0] = *(const bf16x8*)(aptr + k);
            ra[1] = *(const bf16x8*)(aptr + k + 8);
            #pragma unroll
            for (int i = 0; i < 4; ++i) { rbA[i] = *(const f32x4v*)(bptrA + k + i * 4); rbB[i] = *(const f32x4v*)(bptrB + k + i * 4); }
        }

        bf16x8 af[4];
        #pragma unroll
        for (int mf = 0; mf < 4; ++mf)
            af[mf] = *(const bf16x8*)&sA[wr * 64 + mf * 16 + frow][fk];
        #pragma unroll
        for (int nf = 0; nf < 8; ++nf) {
            bf16x8 bfv = *(const bf16x8*)&sB[wc * 128 + nf * 16 + frow][fk];
            #pragma unroll
            for (int mf = 0; mf < 4; ++mf)
                acc[mf][nf] = __builtin_amdgcn_mfma_f32_16x16x32_bf16(af[mf], bfv, acc[mf][nf], 0, 0, 0);
        }
    }

    const int r4 = (lane >> 4) * 4;
    #pragma unroll
    for (int mf = 0; mf < 4; ++mf)
        #pragma unroll
        for (int nf = 0; nf < 8; ++nf)
            #pragma unroll
            for (int j = 0; j < 4; ++j) {
                int rr = wr * 64 + mf * 16 + r4 + j;
                if (rr < rows) {
                    int col = n0 + wc * 128 + nf * 16 + (lane & 15);
                    atomicAdd(out + (size_t)sTok[rr] * H_DIM + col, acc[mf][nf][j]);
                }
            }
}

// ---------------- launch ----------------
extern "C" void kernel_launch(void* const* d_in, const int* in_sizes, int n_in,
                              void* d_out, int out_size, void* d_ws, size_t ws_size,
                              hipStream_t stream)
{
    (void)in_sizes; (void)n_in;
    const float* X     = (const float*)d_in[0];
    const float* topw  = (const float*)d_in[1];
    const int*   topid = (const int*)d_in[2];
    const float* Wi0   = (const float*)d_in[3];
    const float* Wi1   = (const float*)d_in[4];
    const float* Wo    = (const float*)d_in[5];
    float* out = (float*)d_out;

    char* ws = (char*)d_ws;
    int*   pair_token  = (int*)ws;
    float* pair_w      = (float*)(ws + NPAIR * 4);
    int*   tile_expert = (int*)(ws + NPAIR * 8);
    int*   tile_row0   = tile_expert + MAXT;
    int*   tile_rows   = tile_row0 + MAXT;
    int*   t1_expert   = tile_rows + MAXT;
    int*   t1_row0     = t1_expert + MAXT1;
    int*   t1_rows     = t1_row0 + MAXT1;

    route_kernel<<<1, 256, 0, stream>>>(topid, topw, pair_token, pair_w,
                                        tile_expert, tile_row0, tile_rows,
                                        t1_expert, t1_row0, t1_rows);

    if (ws_size >= NEED_NEW) {
        short* Ht  = (short*)(ws + HT_OFF);
        short* At  = (short*)(ws + AT_OFF);
        short* Ws  = (short*)(ws + WS_OFF);
        short* Wot = (short*)(ws + W0_OFF);   // overlays At/Ws (dead after gemm1f)

        aprep128_kernel<<<2304, 256, 0, stream>>>(X, pair_token, tile_row0, tile_rows, At);
        wsprep_kernel<<<8192, 256, 0, stream>>>(Wi0, Wi1, Ws);

        gemm1f_kernel<<<2304, 256, 0, stream>>>(
            At, Ws, pair_w, tile_expert, tile_row0, tile_rows, Ht);

        hipMemsetAsync(d_out, 0, (size_t)out_size * sizeof(float), stream);

        woprep2_kernel<<<4096, 256, 0, stream>>>(Wo, Wot);

        gemm2s_kernel<<<2304, 256, 0, stream>>>(
            Ht, Wot, pair_token, tile_expert, tile_row0, tile_rows, out);
    } else {
        short* Hbuf = (short*)(ws + (1 << 20));
        short* Xbf  = (short*)d_out;

        cvt_kernel<<<T_TOK * H_DIM / (256 * 8), 256, 0, stream>>>(X, Xbf);

        gemm1_kernel<<<dim3(MAXT1, I_DIM / BN1), 512, 0, stream>>>(
            Xbf, Wi0, Wi1, pair_token, pair_w, t1_expert, t1_row0, t1_rows, Hbuf);

        hipMemsetAsync(d_out, 0, (size_t)out_size * sizeof(float), stream);

        gemm2_kernel<<<dim3(MAXT, H_DIM / 256), 256, 0, stream>>>(
            Hbuf, Wo, pair_token, tile_expert, tile_row0, tile_rows, out);
    }
}